// Round 1
// baseline (11600.459 us; speedup 1.0000x reference)
//
#include <hip/hip_runtime.h>
#include <cstdint>
#include <cstddef>

typedef __bf16 bf16;
typedef __attribute__((ext_vector_type(8))) __bf16 bf16x8;
typedef __attribute__((ext_vector_type(4))) float f32x4;
typedef __attribute__((ext_vector_type(4))) unsigned u32x4;

#define DEV static __device__ __forceinline__

DEV float sigm_(float x) { return 1.f / (1.f + __expf(-x)); }
DEV float tanhf_(float x) {
  float e = __expf(-2.f * fabsf(x));
  float t = (1.f - e) / (1.f + e);
  return x < 0.f ? -t : t;
}

DEV void gload_lds16(const bf16* g, bf16* l) {
  __builtin_amdgcn_global_load_lds((const __attribute__((address_space(1))) void*)g,
                                   (__attribute__((address_space(3))) void*)l, 16, 0, 0);
}

// ---------------------------------------------------------------------------
// repack kernels (unchanged)
// ---------------------------------------------------------------------------
__global__ void k_frames(const float* __restrict__ S, bf16* __restrict__ dst) {
  int idx = blockIdx.x * 256 + threadIdx.x;
  if (idx >= 38400 * 576) return;
  int r = idx / 576, c = idx - r * 576;
  int t = r >> 6, b = r & 63;
  float v = (t == 0 || c >= 552) ? 0.f : S[((size_t)(t - 1) * 64 + b) * 552 + c];
  dst[idx] = (bf16)v;
}

__global__ void k_pad2d(const float* __restrict__ src, bf16* __restrict__ dst,
                        int N, int Cdst, int Csrc, int Rsrc, int sstride) {
  int idx = blockIdx.x * 256 + threadIdx.x;
  if (idx >= N) return;
  int r = idx / Cdst, c = idx - r * Cdst;
  float v = (r < Rsrc && c < Csrc) ? src[(size_t)r * sstride + c] : 0.f;
  dst[idx] = (bf16)v;
}

__global__ void k_w0c(const float* __restrict__ Whh0, const float* __restrict__ Wih0,
                      bf16* __restrict__ dst) {
  int idx = blockIdx.x * 256 + threadIdx.x;
  if (idx >= 4096 * 1280) return;
  int r = idx / 1280, k = idx - r * 1280;
  float v = (k < 1024) ? Whh0[(size_t)r * 1024 + k] : Wih0[(size_t)r * 384 + (k - 1024)];
  dst[idx] = (bf16)v;
}

__global__ void k_w1c(const float* __restrict__ Wih1, const float* __restrict__ Whh1,
                      bf16* __restrict__ dst) {
  int idx = blockIdx.x * 256 + threadIdx.x;
  if (idx >= 4096 * 2048) return;
  int r = idx / 2048, k = idx - r * 2048;
  float v = (k < 1024) ? Wih1[(size_t)r * 1024 + k] : Whh1[(size_t)r * 1024 + (k - 1024)];
  dst[idx] = (bf16)v;
}

__global__ void k_convw(const float* __restrict__ src, bf16* __restrict__ dst,
                        int N, int Cpad, int Cisrc, int Cosrc) {
  int idx = blockIdx.x * 256 + threadIdx.x;
  if (idx >= N) return;
  int per = 5 * Cpad;
  int co = idx / per, rem = idx - co * per;
  int tap = rem / Cpad, ci = rem - tap * Cpad;
  float v = (co < Cosrc && ci < Cisrc) ? src[((size_t)co * Cisrc + ci) * 5 + tap] : 0.f;
  dst[idx] = (bf16)v;
}

// zero pad rows {0,1,602,603} of X0[64][604][576], X1/X2[64][604][512]
__global__ void k_zpad(bf16* __restrict__ X0, bf16* __restrict__ X1, bf16* __restrict__ X2) {
  int idx = blockIdx.x * 256 + threadIdx.x;
  if (idx >= 64 * 4 * 1600) return;
  int per = 4 * 1600;
  int b = idx / per, rem = idx - b * per;
  int rr = rem / 1600, c = rem - rr * 1600;
  int row = (rr < 2) ? rr : 600 + rr;
  if (c < 576) X0[((size_t)b * 604 + row) * 576 + c] = (bf16)0.f;
  else if (c < 1088) X1[((size_t)b * 604 + row) * 512 + (c - 576)] = (bf16)0.f;
  else X2[((size_t)b * 604 + row) * 512 + (c - 1088)] = (bf16)0.f;
}

// ---------------------------------------------------------------------------
// generic NT GEMM (unchanged)
// ---------------------------------------------------------------------------
enum { M_RELU = 0, M_LINEAR = 1, M_CONVT = 2, M_CONVF = 3 };

template <int MODE>
__global__ __launch_bounds__(256) void gemm_k(
    const bf16* __restrict__ A, const bf16* __restrict__ B, int Ktot, int Kstride,
    int Brows, const float* __restrict__ bias,
    bf16* __restrict__ outB, int outStride, int colP, int colOff,
    float* __restrict__ outF, bf16* __restrict__ outX) {
  const int tid = threadIdx.x;
  const int lane = tid & 63, wv = tid >> 6;
  const int n0 = blockIdx.x * 128, m0 = blockIdx.y * 128;
  const int bz = blockIdx.z;
  __shared__ bf16 As[128 * 64];
  __shared__ bf16 Bs[128 * 64];
  f32x4 acc[4][4] = {};
  const int wr = wv >> 1, wc = wv & 1;
  int tap = 0, ci0 = 0;

  for (int kb = 0; kb < Ktot; kb += 64) {
#pragma unroll
    for (int j = 0; j < 4; ++j) {
      int rt = wv * 32 + j * 8 + (lane >> 3);
      const bf16* gp;
      if (MODE == M_CONVT || MODE == M_CONVF) {
        int l = m0 + rt;
        if (l > 599) l = 599;
        gp = A + ((size_t)(bz * 604 + l + tap)) * Kstride + ci0 + (lane & 7) * 8;
      } else {
        gp = A + (size_t)(m0 + rt) * Kstride + kb + (lane & 7) * 8;
      }
      gload_lds16(gp, &As[(wv * 32 + j * 8) * 64]);
    }
#pragma unroll
    for (int j = 0; j < 4; ++j) {
      int rn = n0 + wv * 32 + j * 8 + (lane >> 3);
      if (rn >= Brows) rn = Brows - 1;
      const bf16* gp = B + (size_t)rn * Ktot + kb + (lane & 7) * 8;
      gload_lds16(gp, &Bs[(wv * 32 + j * 8) * 64]);
    }
    __syncthreads();
#pragma unroll
    for (int ks = 0; ks < 2; ++ks) {
      const int ko = ks * 32 + (lane >> 4) * 8;
      bf16x8 af[4], bfr[4];
#pragma unroll
      for (int i = 0; i < 4; ++i) {
        af[i] = *(const bf16x8*)&As[(wr * 64 + i * 16 + (lane & 15)) * 64 + ko];
        bfr[i] = *(const bf16x8*)&Bs[(wc * 64 + i * 16 + (lane & 15)) * 64 + ko];
      }
#pragma unroll
      for (int mi = 0; mi < 4; ++mi)
#pragma unroll
        for (int ni = 0; ni < 4; ++ni)
          acc[mi][ni] = __builtin_amdgcn_mfma_f32_16x16x32_bf16(af[mi], bfr[ni], acc[mi][ni], 0, 0, 0);
    }
    __syncthreads();
    ci0 += 64;
    if (ci0 == Kstride) { ci0 = 0; ++tap; }
  }

  const int r0 = (lane >> 4) * 4, cc = lane & 15;
#pragma unroll
  for (int mi = 0; mi < 4; ++mi) {
#pragma unroll
    for (int ni = 0; ni < 4; ++ni) {
#pragma unroll
      for (int r = 0; r < 4; ++r) {
        float v = acc[mi][ni][r];
        int gr = m0 + wr * 64 + mi * 16 + r0 + r;
        int gc = n0 + wc * 64 + ni * 16 + cc;
        if (MODE == M_RELU) {
          v += bias[gc];
          v = fmaxf(v, 0.f);
          outB[(size_t)(gr >> 6) * outStride + (size_t)(gr & 63) * colP + colOff + gc] = (bf16)v;
        } else if (MODE == M_LINEAR) {
          if (gc < 552) {
            v += bias[gc];
            int t = gr >> 6, b = gr & 63;
            outF[(size_t)gr * 552 + gc] = v;
            outX[((size_t)b * 604 + t + 2) * 576 + gc] = (bf16)v;
          }
        } else if (MODE == M_CONVT) {
          if (gr < 600) {
            v = tanhf_(v + bias[gc]);
            outB[((size_t)bz * 604 + gr + 2) * 512 + gc] = (bf16)v;
          }
        } else {
          if (gr < 600 && gc < 552) {
            v += bias[gc];
            float* p = outF + ((size_t)gr * 64 + bz) * 552 + gc;
            *p += v;
          }
        }
      }
    }
  }
}

// ---------------------------------------------------------------------------
// LSTM scan v4: per-WAVE fine-grained producer waits (each wave polls only the
// flags covering its K-slice, fences, and immediately starts its A-loads/MFMAs
// -> straggler jitter overlaps with useful work instead of gating the whole
// block). Producer tail moved off the critical path of waves 1-3: cell threads
// stage packed h pairs in LDS; wave 0 alone issues 64 coalesced 16B sc0/sc1
// stores + vmcnt(0) + flag, while the other waves begin the next step's poll.
// 2 block barriers per step (was 3), no block-wide wait.
// C0[601][64][1280]: [0:1024)=h0[t-1] (row0=0), [1024:1280)=pre2[t]
// H1[602][64][1024]: h1[t] at row t+2 (rows 0,1 = 0)
// groups: g = layer*2 + mh (64 blocks each). flags[g][64] = step counter.
// ---------------------------------------------------------------------------
template <int LAYER>
DEV void scan_impl(bf16* __restrict__ C0, bf16* __restrict__ H1,
                   const bf16* __restrict__ W, const float* __restrict__ bi,
                   const float* __restrict__ bh, unsigned* __restrict__ flags,
                   float* gb, u32x4* hst4, int u0, int b0, int mh, int ub) {
  constexpr int KT = LAYER ? 2048 : 1280;
  constexpr int NKS = LAYER ? 16 : 10;
  const int tid = threadIdx.x, lane = tid & 63, w = tid >> 6;
  const int kb = w * (KT / 4);

  // weight B-fragments -> registers/AGPRs, loaded once
  bf16x8 wreg[4][NKS];
#pragma unroll
  for (int gi = 0; gi < 4; ++gi)
#pragma unroll
    for (int ks = 0; ks < NKS; ++ks)
      wreg[gi][ks] = *(const bf16x8*)(W + (size_t)(gi * 1024 + u0 + (lane & 15)) * KT +
                                      kb + ks * 32 + (lane >> 4) * 8);

  const int bl = tid >> 3, uu = (tid & 7) * 2;
  float bs[4][2];
#pragma unroll
  for (int g = 0; g < 4; ++g)
#pragma unroll
    for (int j = 0; j < 2; ++j) {
      int rw = g * 1024 + u0 + uu + j;
      bs[g][j] = bi[rw] + bh[rw];
    }
  float cst[2] = {0.f, 0.f};

  unsigned* flO = flags + (LAYER * 2 + mh) * 64;  // own group (publish + h recurrence)
  unsigned* flP = flags + mh * 64;                // L0 group, same batch half

  // per-wave producer-flag slice for this wave's K range
  unsigned* flA;
  int pA0, cA;
  int thrAdd;  // threshold = t + thrAdd
  if (!LAYER) {
    // wave w covers k in [w*320, w*320+320): h units -> ub [20w, 20w+cA)
    flA = flO;
    pA0 = w * 20;
    cA = (w < 3) ? 20 : 4;  // wave 3: ubs 60..63 (rest is precomputed pre2)
    thrAdd = 0;             // needs h0[t-1] -> flag >= t
  } else if (w < 2) {
    // h0[t] part: ub [32w, 32w+32) of L0 group, flag >= t+1
    flA = flP;
    pA0 = w * 32;
    cA = 32;
    thrAdd = 1;
  } else {
    // h1[t-1] part: ub [32(w-2), ...) of own group, flag >= t
    flA = flO;
    pA0 = (w - 2) * 32;
    cA = 32;
    thrAdd = 0;
  }
  const bool pollAct = lane < cA;

  const int r0 = lane & 15, q8 = (lane >> 4) * 8;

  for (int t = 0; t < 600; ++t) {
    // ---- per-wave wait: only this wave's K-slice producers
    if (LAYER || t > 0) {
      const unsigned thr = (unsigned)(t + thrAdd);
      for (;;) {
        unsigned f = pollAct
            ? __hip_atomic_load(&flA[pA0 + lane], __ATOMIC_RELAXED, __HIP_MEMORY_SCOPE_AGENT)
            : 0xFFFFFFFFu;
        if (!__ballot(f < thr)) break;
        __builtin_amdgcn_s_sleep(1);
      }
      __builtin_amdgcn_fence(__ATOMIC_ACQUIRE, "agent");  // invalidate stale lines
    }

    // ---- A fragments straight from global (16 rows x 64B segments, coalesced)
    const bf16* A0;
    int RS;
    if (!LAYER) {
      RS = 1280;
      A0 = C0 + (size_t)t * 81920 + (size_t)(b0 + r0) * 1280 + kb + q8;
    } else if (w < 2) {
      RS = 1280;
      A0 = C0 + (size_t)(t + 1) * 81920 + (size_t)(b0 + r0) * 1280 + w * 512 + q8;
    } else {
      RS = 1024;
      A0 = H1 + (size_t)(t + 1) * 65536 + (size_t)(b0 + r0) * 1024 + (w - 2) * 512 + q8;
    }
    const bf16* A1 = A0 + 16 * RS;

    f32x4 acc[4][2] = {};
#pragma unroll
    for (int ks = 0; ks < NKS; ++ks) {
      bf16x8 a0 = *(const bf16x8*)(A0 + ks * 32);
      bf16x8 a1 = *(const bf16x8*)(A1 + ks * 32);
#pragma unroll
      for (int gi = 0; gi < 4; ++gi) {
        acc[gi][0] = __builtin_amdgcn_mfma_f32_16x16x32_bf16(a0, wreg[gi][ks], acc[gi][0], 0, 0, 0);
        acc[gi][1] = __builtin_amdgcn_mfma_f32_16x16x32_bf16(a1, wreg[gi][ks], acc[gi][1], 0, 0, 0);
      }
    }

    // ---- k-partials to LDS: row = (w*4+gi)*16 + unit, col = batch-local (stride 36)
    const int un = lane & 15, qb = (lane >> 4) * 4;
#pragma unroll
    for (int gi = 0; gi < 4; ++gi)
#pragma unroll
      for (int b2 = 0; b2 < 2; ++b2)
        *(f32x4*)&gb[((w * 4 + gi) * 16 + un) * 36 + b2 * 16 + qb] = acc[gi][b2];
    __syncthreads();

    // ---- cell update: thread = (batch bl 0..31, units uu..uu+1), c in regs
    float hv[2];
#pragma unroll
    for (int j = 0; j < 2; ++j) {
      const int u = uu + j;
      float s[4];
#pragma unroll
      for (int g = 0; g < 4; ++g) {
        float acc_s = 0.f;
#pragma unroll
        for (int ww = 0; ww < 4; ++ww) acc_s += gb[((ww * 4 + g) * 16 + u) * 36 + bl];
        s[g] = acc_s + bs[g][j];
      }
      float c = sigm_(s[1]) * cst[j] + sigm_(s[0]) * tanhf_(s[2]);
      cst[j] = c;
      hv[j] = sigm_(s[3]) * tanhf_(c);
    }
    union { bf16 h2[2]; unsigned u32; } pk;
    pk.h2[0] = (bf16)hv[0];
    pk.h2[1] = (bf16)hv[1];
    ((unsigned*)hst4)[bl * 8 + (uu >> 1)] = pk.u32;  // stage h in LDS
    __syncthreads();  // hstage ready; gb fully consumed (next-step writes safe)

    // ---- wave 0 publishes: 64 x 16B coalesced write-through stores + flag.
    // waves 1-3 fall straight into the next step's poll.
    if (w == 0) {
      const int row = lane >> 1, half = lane & 1;
      u32x4 hv4 = hst4[row * 2 + half];
      bf16* dp = LAYER
          ? H1 + (size_t)(t + 2) * 65536 + (size_t)(b0 + row) * 1024 + u0 + half * 8
          : C0 + (size_t)(t + 1) * 81920 + (size_t)(b0 + row) * 1280 + u0 + half * 8;
      asm volatile("global_store_dwordx4 %0, %1, off sc0 sc1" :: "v"(dp), "v"(hv4) : "memory");
      asm volatile("s_waitcnt vmcnt(0)" ::: "memory");  // h at coherence point
      if (lane == 0)
        __hip_atomic_store(&flO[ub], (unsigned)(t + 1), __ATOMIC_RELAXED, __HIP_MEMORY_SCOPE_AGENT);
    }
  }
}

__global__ __launch_bounds__(256, 1) void lstm_k(
    bf16* __restrict__ C0, bf16* __restrict__ H1,
    const bf16* __restrict__ W0, const bf16* __restrict__ W1,
    const float* __restrict__ bi0, const float* __restrict__ bh0,
    const float* __restrict__ bi1, const float* __restrict__ bh1,
    unsigned* __restrict__ flags) {
  __shared__ float gb[256 * 36];   // 36.9 KB gate partials
  __shared__ u32x4 hst4[64];       // 1 KB packed-h staging (32 rows x 32B)
  const int bid = blockIdx.x;
  const int layer = bid >> 7, sub = bid & 127;
  const int mh = sub >> 6, ub = sub & 63;
  const int u0 = ub * 16, b0 = mh * 32;
  if (layer == 0)
    scan_impl<0>(C0, H1, W0, bi0, bh0, flags, gb, hst4, u0, b0, mh, ub);
  else
    scan_impl<1>(C0, H1, W1, bi1, bh1, flags, gb, hst4, u0, b0, mh, ub);
}

// ---------------------------------------------------------------------------
// host
// ---------------------------------------------------------------------------
static inline unsigned gdiv(size_t n) { return (unsigned)((n + 255) / 256); }

extern "C" void kernel_launch(void* const* d_in, const int* in_sizes, int n_in,
                              void* d_out, int out_size, void* d_ws, size_t ws_size,
                              hipStream_t stream) {
  const float* S = (const float*)d_in[0];
  const float* preW1 = (const float*)d_in[1];
  const float* preb1 = (const float*)d_in[2];
  const float* preW2 = (const float*)d_in[3];
  const float* preb2 = (const float*)d_in[4];
  const float* Wih0 = (const float*)d_in[5];
  const float* Whh0 = (const float*)d_in[6];
  const float* bih0 = (const float*)d_in[7];
  const float* bhh0 = (const float*)d_in[8];
  const float* Wih1 = (const float*)d_in[9];
  const float* Whh1 = (const float*)d_in[10];
  const float* bih1 = (const float*)d_in[11];
  const float* bhh1 = (const float*)d_in[12];
  const float* linW = (const float*)d_in[13];
  const float* linb = (const float*)d_in[14];
  const float* cw1 = (const float*)d_in[15];
  const float* cb1 = (const float*)d_in[16];
  const float* cw2 = (const float*)d_in[17];
  const float* cb2 = (const float*)d_in[18];
  const float* cw3 = (const float*)d_in[19];
  const float* cb3 = (const float*)d_in[20];
  const float* cw4 = (const float*)d_in[21];
  const float* cb4 = (const float*)d_in[22];
  const float* cw5 = (const float*)d_in[23];
  const float* cb5 = (const float*)d_in[24];
  float* out = (float*)d_out;

  char* ws = (char*)d_ws;
  size_t off = 0;
  auto alloc = [&](size_t bytes) -> char* {
    char* p = ws + off;
    off += (bytes + 255) & ~(size_t)255;
    return p;
  };
  unsigned* flags = (unsigned*)alloc(1024);  // 4 groups x 64 flags
  bf16* H1 = (bf16*)alloc(602ull * 64 * 1024 * 2);
  bf16* frames = (bf16*)alloc(38400ull * 576 * 2);
  bf16* pre1 = (bf16*)alloc(38400ull * 256 * 2);
  bf16* W0c = (bf16*)alloc(4096ull * 1280 * 2);
  bf16* W1c = (bf16*)alloc(4096ull * 2048 * 2);
  bf16* pW1b = (bf16*)alloc(256ull * 576 * 2);
  bf16* pW2b = (bf16*)alloc(256ull * 256 * 2);
  bf16* linWb = (bf16*)alloc(576ull * 1024 * 2);
  bf16* c1r = (bf16*)alloc(512ull * 5 * 576 * 2);
  bf16* c2r = (bf16*)alloc(512ull * 5 * 512 * 2);
  bf16* c3r = (bf16*)alloc(512ull * 5 * 512 * 2);
  bf16* c4r = (bf16*)alloc(512ull * 5 * 512 * 2);
  bf16* c5r = (bf16*)alloc(576ull * 5 * 512 * 2);
  bf16* X0 = (bf16*)alloc(64ull * 604 * 576 * 2);
  bf16* X1 = (bf16*)alloc(64ull * 604 * 512 * 2);
  bf16* X2 = (bf16*)alloc(64ull * 604 * 512 * 2);
  bf16* C0 = X0;  // C0[601][64][1280] aliases X0..X2 (dead until after lstm)

  // zero: flags + H1 rows 0,1 ; C0 row 0
  hipMemsetAsync(ws, 0, 1024 + 2ull * 64 * 1024 * 2, stream);
  hipMemsetAsync(C0, 0, 64ull * 1280 * 2, stream);

  // repacks
  k_frames<<<gdiv(38400ull * 576), 256, 0, stream>>>(S, frames);
  k_pad2d<<<gdiv(256 * 576), 256, 0, stream>>>(preW1, pW1b, 256 * 576, 576, 552, 256, 552);
  k_pad2d<<<gdiv(256 * 256), 256, 0, stream>>>(preW2, pW2b, 256 * 256, 256, 256, 256, 256);
  k_pad2d<<<gdiv(576 * 1024), 256, 0, stream>>>(linW, linWb, 576 * 1024, 1024, 1024, 552, 1152);
  k_w0c<<<gdiv(4096ull * 1280), 256, 0, stream>>>(Whh0, Wih0, W0c);
  k_w1c<<<gdiv(4096ull * 2048), 256, 0, stream>>>(Wih1, Whh1, W1c);
  k_convw<<<gdiv(512ull * 5 * 576), 256, 0, stream>>>(cw1, c1r, 512 * 5 * 576, 576, 552, 512);
  k_convw<<<gdiv(512ull * 5 * 512), 256, 0, stream>>>(cw2, c2r, 512 * 5 * 512, 512, 512, 512);
  k_convw<<<gdiv(512ull * 5 * 512), 256, 0, stream>>>(cw3, c3r, 512 * 5 * 512, 512, 512, 512);
  k_convw<<<gdiv(512ull * 5 * 512), 256, 0, stream>>>(cw4, c4r, 512 * 5 * 512, 512, 512, 512);
  k_convw<<<gdiv(576ull * 5 * 512), 256, 0, stream>>>(cw5, c5r, 576 * 5 * 512, 512, 512, 552);

  // prenet: pre1 = relu(frames@W1^T+b1); C0[t][b][1024:1280] = relu(pre1@W2^T+b2)
  gemm_k<M_RELU><<<dim3(2, 300, 1), 256, 0, stream>>>(frames, pW1b, 576, 576, 256, preb1,
                                                      pre1, 16384, 256, 0, nullptr, nullptr);
  gemm_k<M_RELU><<<dim3(2, 300, 1), 256, 0, stream>>>(pre1, pW2b, 256, 256, 256, preb2,
                                                      C0, 81920, 1280, 1024, nullptr, nullptr);
  // sequential 2-layer LSTM (persistent, 256 blocks, per-wave flag-synced)
  lstm_k<<<dim3(256), 256, 0, stream>>>(C0, H1, W0c, W1c, bih0, bhh0, bih1, bhh1, flags);
  // zero conv pad rows (X bufs were aliased by C0)
  k_zpad<<<gdiv(64 * 4 * 1600), 256, 0, stream>>>(X0, X1, X2);
  // S_pred = h1 @ linW^T + lin_b ; h1[t*64+b] = H1 + 2*64*1024 offset
  gemm_k<M_LINEAR><<<dim3(5, 300, 1), 256, 0, stream>>>(H1 + 131072, linWb, 1024, 1024, 576, linb,
                                                        nullptr, 0, 0, 0, out, X0);
  // postnet
  gemm_k<M_CONVT><<<dim3(4, 5, 64), 256, 0, stream>>>(X0, c1r, 2880, 576, 512, cb1,
                                                      X1, 0, 0, 0, nullptr, nullptr);
  gemm_k<M_CONVT><<<dim3(4, 5, 64), 256, 0, stream>>>(X1, c2r, 2560, 512, 512, cb2,
                                                      X2, 0, 0, 0, nullptr, nullptr);
  gemm_k<M_CONVT><<<dim3(4, 5, 64), 256, 0, stream>>>(X2, c3r, 2560, 512, 512, cb3,
                                                      X1, 0, 0, 0, nullptr, nullptr);
  gemm_k<M_CONVT><<<dim3(4, 5, 64), 256, 0, stream>>>(X1, c4r, 2560, 512, 512, cb4,
                                                      X2, 0, 0, 0, nullptr, nullptr);
  gemm_k<M_CONVF><<<dim3(5, 5, 64), 256, 0, stream>>>(X2, c5r, 2560, 512, 576, cb5,
                                                      nullptr, 0, 0, 0, out, nullptr);
  (void)in_sizes; (void)n_in; (void)out_size; (void)ws_size;
}

// Round 2
// 6055.803 us; speedup vs baseline: 1.9156x; 1.9156x over previous
//
#include <hip/hip_runtime.h>
#include <cstdint>
#include <cstddef>

typedef __bf16 bf16;
typedef __attribute__((ext_vector_type(8))) __bf16 bf16x8;
typedef __attribute__((ext_vector_type(4))) float f32x4;

#define DEV static __device__ __forceinline__

DEV float sigm_(float x) { return 1.f / (1.f + __expf(-x)); }
DEV float tanhf_(float x) {
  float e = __expf(-2.f * fabsf(x));
  float t = (1.f - e) / (1.f + e);
  return x < 0.f ? -t : t;
}

DEV void gload_lds16(const bf16* g, bf16* l) {
  __builtin_amdgcn_global_load_lds((const __attribute__((address_space(1))) void*)g,
                                   (__attribute__((address_space(3))) void*)l, 16, 0, 0);
}

// ---------------------------------------------------------------------------
// repack kernels
// ---------------------------------------------------------------------------
__global__ void k_frames(const float* __restrict__ S, bf16* __restrict__ dst) {
  int idx = blockIdx.x * 256 + threadIdx.x;
  if (idx >= 38400 * 576) return;
  int r = idx / 576, c = idx - r * 576;
  int t = r >> 6, b = r & 63;
  float v = (t == 0 || c >= 552) ? 0.f : S[((size_t)(t - 1) * 64 + b) * 552 + c];
  dst[idx] = (bf16)v;
}

__global__ void k_pad2d(const float* __restrict__ src, bf16* __restrict__ dst,
                        int N, int Cdst, int Csrc, int Rsrc, int sstride) {
  int idx = blockIdx.x * 256 + threadIdx.x;
  if (idx >= N) return;
  int r = idx / Cdst, c = idx - r * Cdst;
  float v = (r < Rsrc && c < Csrc) ? src[(size_t)r * sstride + c] : 0.f;
  dst[idx] = (bf16)v;
}

__global__ void k_w0c(const float* __restrict__ Whh0, const float* __restrict__ Wih0,
                      bf16* __restrict__ dst) {
  int idx = blockIdx.x * 256 + threadIdx.x;
  if (idx >= 4096 * 1280) return;
  int r = idx / 1280, k = idx - r * 1280;
  float v = (k < 1024) ? Whh0[(size_t)r * 1024 + k] : Wih0[(size_t)r * 384 + (k - 1024)];
  dst[idx] = (bf16)v;
}

__global__ void k_w1c(const float* __restrict__ Wih1, const float* __restrict__ Whh1,
                      bf16* __restrict__ dst) {
  int idx = blockIdx.x * 256 + threadIdx.x;
  if (idx >= 4096 * 2048) return;
  int r = idx / 2048, k = idx - r * 2048;
  float v = (k < 1024) ? Wih1[(size_t)r * 1024 + k] : Whh1[(size_t)r * 1024 + (k - 1024)];
  dst[idx] = (bf16)v;
}

__global__ void k_convw(const float* __restrict__ src, bf16* __restrict__ dst,
                        int N, int Cpad, int Cisrc, int Cosrc) {
  int idx = blockIdx.x * 256 + threadIdx.x;
  if (idx >= N) return;
  int per = 5 * Cpad;
  int co = idx / per, rem = idx - co * per;
  int tap = rem / Cpad, ci = rem - tap * Cpad;
  float v = (co < Cosrc && ci < Cisrc) ? src[((size_t)co * Cisrc + ci) * 5 + tap] : 0.f;
  dst[idx] = (bf16)v;
}

// zero pad rows {0,1,602,603} of X0[64][604][576], X1/X2[64][604][512]
__global__ void k_zpad(bf16* __restrict__ X0, bf16* __restrict__ X1, bf16* __restrict__ X2) {
  int idx = blockIdx.x * 256 + threadIdx.x;
  if (idx >= 64 * 4 * 1600) return;
  int per = 4 * 1600;
  int b = idx / per, rem = idx - b * per;
  int rr = rem / 1600, c = rem - rr * 1600;
  int row = (rr < 2) ? rr : 600 + rr;
  if (c < 576) X0[((size_t)b * 604 + row) * 576 + c] = (bf16)0.f;
  else if (c < 1088) X1[((size_t)b * 604 + row) * 512 + (c - 576)] = (bf16)0.f;
  else X2[((size_t)b * 604 + row) * 512 + (c - 1088)] = (bf16)0.f;
}

// ---------------------------------------------------------------------------
// generic NT GEMM (unchanged)
// ---------------------------------------------------------------------------
enum { M_RELU = 0, M_LINEAR = 1, M_CONVT = 2, M_CONVF = 3 };

template <int MODE>
__global__ __launch_bounds__(256) void gemm_k(
    const bf16* __restrict__ A, const bf16* __restrict__ B, int Ktot, int Kstride,
    int Brows, const float* __restrict__ bias,
    bf16* __restrict__ outB, int outStride, int colP, int colOff,
    float* __restrict__ outF, bf16* __restrict__ outX) {
  const int tid = threadIdx.x;
  const int lane = tid & 63, wv = tid >> 6;
  const int n0 = blockIdx.x * 128, m0 = blockIdx.y * 128;
  const int bz = blockIdx.z;
  __shared__ bf16 As[128 * 64];
  __shared__ bf16 Bs[128 * 64];
  f32x4 acc[4][4] = {};
  const int wr = wv >> 1, wc = wv & 1;
  int tap = 0, ci0 = 0;

  for (int kb = 0; kb < Ktot; kb += 64) {
#pragma unroll
    for (int j = 0; j < 4; ++j) {
      int rt = wv * 32 + j * 8 + (lane >> 3);
      const bf16* gp;
      if (MODE == M_CONVT || MODE == M_CONVF) {
        int l = m0 + rt;
        if (l > 599) l = 599;
        gp = A + ((size_t)(bz * 604 + l + tap)) * Kstride + ci0 + (lane & 7) * 8;
      } else {
        gp = A + (size_t)(m0 + rt) * Kstride + kb + (lane & 7) * 8;
      }
      gload_lds16(gp, &As[(wv * 32 + j * 8) * 64]);
    }
#pragma unroll
    for (int j = 0; j < 4; ++j) {
      int rn = n0 + wv * 32 + j * 8 + (lane >> 3);
      if (rn >= Brows) rn = Brows - 1;
      const bf16* gp = B + (size_t)rn * Ktot + kb + (lane & 7) * 8;
      gload_lds16(gp, &Bs[(wv * 32 + j * 8) * 64]);
    }
    __syncthreads();
#pragma unroll
    for (int ks = 0; ks < 2; ++ks) {
      const int ko = ks * 32 + (lane >> 4) * 8;
      bf16x8 af[4], bfr[4];
#pragma unroll
      for (int i = 0; i < 4; ++i) {
        af[i] = *(const bf16x8*)&As[(wr * 64 + i * 16 + (lane & 15)) * 64 + ko];
        bfr[i] = *(const bf16x8*)&Bs[(wc * 64 + i * 16 + (lane & 15)) * 64 + ko];
      }
#pragma unroll
      for (int mi = 0; mi < 4; ++mi)
#pragma unroll
        for (int ni = 0; ni < 4; ++ni)
          acc[mi][ni] = __builtin_amdgcn_mfma_f32_16x16x32_bf16(af[mi], bfr[ni], acc[mi][ni], 0, 0, 0);
    }
    __syncthreads();
    ci0 += 64;
    if (ci0 == Kstride) { ci0 = 0; ++tap; }
  }

  const int r0 = (lane >> 4) * 4, cc = lane & 15;
#pragma unroll
  for (int mi = 0; mi < 4; ++mi) {
#pragma unroll
    for (int ni = 0; ni < 4; ++ni) {
#pragma unroll
      for (int r = 0; r < 4; ++r) {
        float v = acc[mi][ni][r];
        int gr = m0 + wr * 64 + mi * 16 + r0 + r;
        int gc = n0 + wc * 64 + ni * 16 + cc;
        if (MODE == M_RELU) {
          v += bias[gc];
          v = fmaxf(v, 0.f);
          outB[(size_t)(gr >> 6) * outStride + (size_t)(gr & 63) * colP + colOff + gc] = (bf16)v;
        } else if (MODE == M_LINEAR) {
          if (gc < 552) {
            v += bias[gc];
            int t = gr >> 6, b = gr & 63;
            outF[(size_t)gr * 552 + gc] = v;
            outX[((size_t)b * 604 + t + 2) * 576 + gc] = (bf16)v;
          }
        } else if (MODE == M_CONVT) {
          if (gr < 600) {
            v = tanhf_(v + bias[gc]);
            outB[((size_t)bz * 604 + gr + 2) * 512 + gc] = (bf16)v;
          }
        } else {
          if (gr < 600 && gc < 552) {
            v += bias[gc];
            float* p = outF + ((size_t)gr * 64 + bz) * 552 + gc;
            *p += v;
          }
        }
      }
    }
  }
}

// ---------------------------------------------------------------------------
// LSTM scan v5 = v3 structure (block-wide wave-0 wait, all-wave publish)
// with two coherence-overhead removals:
//  (a) NO per-step acquire fence. All inter-block data (C0[t] h-section,
//      H1[t]) is WRITE-ONCE: stored via sc1 write-through atomics, drained
//      (vmcnt(0)) before the flag store. A consumer can never hold a stale
//      L1/L2 copy of a line nobody wrote early and it never read (no HW
//      prefetch on CDNA L1/L2). Flags are re-written each step but are
//      polled with agent-scope atomic loads (sc1, L2-bypass) so they never
//      need an invalidate. The __syncthreads() after the poll is the
//      compiler barrier that keeps A-loads from hoisting above the poll.
//  (b) flags padded to 128 B each (one MALL line per flag) — previously
//      64 flags packed into 2 lines were polled by ~192 waves x 64 lanes
//      continuously, serializing on 2 MALL line channels.
// C0[601][64][1280]: [0:1024)=h0[t-1] (row0=0), [1024:1280)=pre2[t]
// H1[602][64][1024]: h1[t] at row t+2 (rows 0,1 = 0)
// groups: g = layer*2 + mh (64 blocks each). flag[g][i] at (g*64+i)*32 u32.
// ---------------------------------------------------------------------------
template <int LAYER>
DEV void scan_impl(bf16* __restrict__ C0, bf16* __restrict__ H1,
                   const bf16* __restrict__ W, const float* __restrict__ bi,
                   const float* __restrict__ bh, unsigned* __restrict__ flags,
                   float* gb, int u0, int b0, int mh, int ub) {
  constexpr int KT = LAYER ? 2048 : 1280;
  constexpr int NKS = LAYER ? 16 : 10;
  const int tid = threadIdx.x, lane = tid & 63, w = tid >> 6;
  const int kb = w * (KT / 4);

  // weight B-fragments -> registers/AGPRs, loaded once
  bf16x8 wreg[4][NKS];
#pragma unroll
  for (int gi = 0; gi < 4; ++gi)
#pragma unroll
    for (int ks = 0; ks < NKS; ++ks)
      wreg[gi][ks] = *(const bf16x8*)(W + (size_t)(gi * 1024 + u0 + (lane & 15)) * KT +
                                      kb + ks * 32 + (lane >> 4) * 8);

  const int bl = tid >> 3, uu = (tid & 7) * 2;
  float bs[4][2];
#pragma unroll
  for (int g = 0; g < 4; ++g)
#pragma unroll
    for (int j = 0; j < 2; ++j) {
      int rw = g * 1024 + u0 + uu + j;
      bs[g][j] = bi[rw] + bh[rw];
    }
  float cst[2] = {0.f, 0.f};

  unsigned* flO = flags + (LAYER * 2 + mh) * 64 * 32;  // own group
  unsigned* flP = flags + mh * 64 * 32;                // L0 group, same batch half

  const int r0 = lane & 15, q8 = (lane >> 4) * 8;

  for (int t = 0; t < 600; ++t) {
    // ---- wait for inputs (wave 0 polls; others park at barrier)
    if (w == 0 && (LAYER || t > 0)) {
      const unsigned tO = (unsigned)t, tP = (unsigned)(t + 1);
      for (;;) {
        bool bad = __hip_atomic_load(&flO[lane << 5], __ATOMIC_RELAXED, __HIP_MEMORY_SCOPE_AGENT) < tO;
        if (LAYER)
          bad |= __hip_atomic_load(&flP[lane << 5], __ATOMIC_RELAXED, __HIP_MEMORY_SCOPE_AGENT) < tP;
        if (!__ballot(bad)) break;
        __builtin_amdgcn_s_sleep(1);
      }
      // no acquire fence: see header comment (write-once data + sc1 flags)
    }
    __syncthreads();

    // ---- A fragments straight from global (16 rows x 64B segments, coalesced)
    const bf16* A0;
    int RS;
    if (!LAYER) {
      RS = 1280;
      A0 = C0 + (size_t)t * 81920 + (size_t)(b0 + r0) * 1280 + kb + q8;
    } else if (w < 2) {
      RS = 1280;
      A0 = C0 + (size_t)(t + 1) * 81920 + (size_t)(b0 + r0) * 1280 + w * 512 + q8;
    } else {
      RS = 1024;
      A0 = H1 + (size_t)(t + 1) * 65536 + (size_t)(b0 + r0) * 1024 + (w - 2) * 512 + q8;
    }
    const bf16* A1 = A0 + 16 * RS;

    f32x4 acc[4][2] = {};
#pragma unroll
    for (int ks = 0; ks < NKS; ++ks) {
      bf16x8 a0 = *(const bf16x8*)(A0 + ks * 32);
      bf16x8 a1 = *(const bf16x8*)(A1 + ks * 32);
#pragma unroll
      for (int gi = 0; gi < 4; ++gi) {
        acc[gi][0] = __builtin_amdgcn_mfma_f32_16x16x32_bf16(a0, wreg[gi][ks], acc[gi][0], 0, 0, 0);
        acc[gi][1] = __builtin_amdgcn_mfma_f32_16x16x32_bf16(a1, wreg[gi][ks], acc[gi][1], 0, 0, 0);
      }
    }

    // ---- k-partials to LDS: row = (w*4+gi)*16 + unit, col = batch-local (stride 36)
    const int un = lane & 15, qb = (lane >> 4) * 4;
#pragma unroll
    for (int gi = 0; gi < 4; ++gi)
#pragma unroll
      for (int b2 = 0; b2 < 2; ++b2)
        *(f32x4*)&gb[((w * 4 + gi) * 16 + un) * 36 + b2 * 16 + qb] = acc[gi][b2];
    __syncthreads();

    // ---- cell update: thread = (batch bl 0..31, units uu..uu+1), c in regs
    float hv[2];
#pragma unroll
    for (int j = 0; j < 2; ++j) {
      const int u = uu + j;
      float s[4];
#pragma unroll
      for (int g = 0; g < 4; ++g) {
        float acc_s = 0.f;
#pragma unroll
        for (int ww = 0; ww < 4; ++ww) acc_s += gb[((ww * 4 + g) * 16 + u) * 36 + bl];
        s[g] = acc_s + bs[g][j];
      }
      float c = sigm_(s[1]) * cst[j] + sigm_(s[0]) * tanhf_(s[2]);
      cst[j] = c;
      hv[j] = sigm_(s[3]) * tanhf_(c);
    }
    union { bf16 h2[2]; unsigned u32; } pk;
    pk.h2[0] = (bf16)hv[0];
    pk.h2[1] = (bf16)hv[1];
    unsigned* dst =
        LAYER ? (unsigned*)(H1 + (size_t)(t + 2) * 65536 + (size_t)(b0 + bl) * 1024 + u0 + uu)
              : (unsigned*)(C0 + (size_t)(t + 1) * 81920 + (size_t)(b0 + bl) * 1280 + u0 + uu);
    __hip_atomic_store(dst, pk.u32, __ATOMIC_RELAXED, __HIP_MEMORY_SCOPE_AGENT);
    asm volatile("s_waitcnt vmcnt(0)" ::: "memory");  // own h-stores at coherence point
    __syncthreads();                                   // all block's h-stores done
    if (tid == 0)
      __hip_atomic_store(&flO[ub << 5], (unsigned)(t + 1), __ATOMIC_RELAXED, __HIP_MEMORY_SCOPE_AGENT);
  }
}

__global__ __launch_bounds__(256, 1) void lstm_k(
    bf16* __restrict__ C0, bf16* __restrict__ H1,
    const bf16* __restrict__ W0, const bf16* __restrict__ W1,
    const float* __restrict__ bi0, const float* __restrict__ bh0,
    const float* __restrict__ bi1, const float* __restrict__ bh1,
    unsigned* __restrict__ flags) {
  __shared__ float gb[256 * 36];  // 36.9 KB gate partials
  const int bid = blockIdx.x;
  const int layer = bid >> 7, sub = bid & 127;
  const int mh = sub >> 6, ub = sub & 63;
  const int u0 = ub * 16, b0 = mh * 32;
  if (layer == 0)
    scan_impl<0>(C0, H1, W0, bi0, bh0, flags, gb, u0, b0, mh, ub);
  else
    scan_impl<1>(C0, H1, W1, bi1, bh1, flags, gb, u0, b0, mh, ub);
}

// ---------------------------------------------------------------------------
// host
// ---------------------------------------------------------------------------
static inline unsigned gdiv(size_t n) { return (unsigned)((n + 255) / 256); }

extern "C" void kernel_launch(void* const* d_in, const int* in_sizes, int n_in,
                              void* d_out, int out_size, void* d_ws, size_t ws_size,
                              hipStream_t stream) {
  const float* S = (const float*)d_in[0];
  const float* preW1 = (const float*)d_in[1];
  const float* preb1 = (const float*)d_in[2];
  const float* preW2 = (const float*)d_in[3];
  const float* preb2 = (const float*)d_in[4];
  const float* Wih0 = (const float*)d_in[5];
  const float* Whh0 = (const float*)d_in[6];
  const float* bih0 = (const float*)d_in[7];
  const float* bhh0 = (const float*)d_in[8];
  const float* Wih1 = (const float*)d_in[9];
  const float* Whh1 = (const float*)d_in[10];
  const float* bih1 = (const float*)d_in[11];
  const float* bhh1 = (const float*)d_in[12];
  const float* linW = (const float*)d_in[13];
  const float* linb = (const float*)d_in[14];
  const float* cw1 = (const float*)d_in[15];
  const float* cb1 = (const float*)d_in[16];
  const float* cw2 = (const float*)d_in[17];
  const float* cb2 = (const float*)d_in[18];
  const float* cw3 = (const float*)d_in[19];
  const float* cb3 = (const float*)d_in[20];
  const float* cw4 = (const float*)d_in[21];
  const float* cb4 = (const float*)d_in[22];
  const float* cw5 = (const float*)d_in[23];
  const float* cb5 = (const float*)d_in[24];
  float* out = (float*)d_out;

  char* ws = (char*)d_ws;
  size_t off = 0;
  auto alloc = [&](size_t bytes) -> char* {
    char* p = ws + off;
    off += (bytes + 255) & ~(size_t)255;
    return p;
  };
  unsigned* flags = (unsigned*)alloc(32768);  // 4 groups x 64 flags x 128B pad
  bf16* H1 = (bf16*)alloc(602ull * 64 * 1024 * 2);
  bf16* frames = (bf16*)alloc(38400ull * 576 * 2);
  bf16* pre1 = (bf16*)alloc(38400ull * 256 * 2);
  bf16* W0c = (bf16*)alloc(4096ull * 1280 * 2);
  bf16* W1c = (bf16*)alloc(4096ull * 2048 * 2);
  bf16* pW1b = (bf16*)alloc(256ull * 576 * 2);
  bf16* pW2b = (bf16*)alloc(256ull * 256 * 2);
  bf16* linWb = (bf16*)alloc(576ull * 1024 * 2);
  bf16* c1r = (bf16*)alloc(512ull * 5 * 576 * 2);
  bf16* c2r = (bf16*)alloc(512ull * 5 * 512 * 2);
  bf16* c3r = (bf16*)alloc(512ull * 5 * 512 * 2);
  bf16* c4r = (bf16*)alloc(512ull * 5 * 512 * 2);
  bf16* c5r = (bf16*)alloc(576ull * 5 * 512 * 2);
  bf16* X0 = (bf16*)alloc(64ull * 604 * 576 * 2);
  bf16* X1 = (bf16*)alloc(64ull * 604 * 512 * 2);
  bf16* X2 = (bf16*)alloc(64ull * 604 * 512 * 2);
  bf16* C0 = X0;  // C0[601][64][1280] aliases X0..X2 (dead until after lstm)

  // zero: flags + H1 rows 0,1 ; C0 row 0
  hipMemsetAsync(ws, 0, 32768 + 2ull * 64 * 1024 * 2, stream);
  hipMemsetAsync(C0, 0, 64ull * 1280 * 2, stream);

  // repacks
  k_frames<<<gdiv(38400ull * 576), 256, 0, stream>>>(S, frames);
  k_pad2d<<<gdiv(256 * 576), 256, 0, stream>>>(preW1, pW1b, 256 * 576, 576, 552, 256, 552);
  k_pad2d<<<gdiv(256 * 256), 256, 0, stream>>>(preW2, pW2b, 256 * 256, 256, 256, 256, 256);
  k_pad2d<<<gdiv(576 * 1024), 256, 0, stream>>>(linW, linWb, 576 * 1024, 1024, 1024, 552, 1152);
  k_w0c<<<gdiv(4096ull * 1280), 256, 0, stream>>>(Whh0, Wih0, W0c);
  k_w1c<<<gdiv(4096ull * 2048), 256, 0, stream>>>(Wih1, Whh1, W1c);
  k_convw<<<gdiv(512ull * 5 * 576), 256, 0, stream>>>(cw1, c1r, 512 * 5 * 576, 576, 552, 512);
  k_convw<<<gdiv(512ull * 5 * 512), 256, 0, stream>>>(cw2, c2r, 512 * 5 * 512, 512, 512, 512);
  k_convw<<<gdiv(512ull * 5 * 512), 256, 0, stream>>>(cw3, c3r, 512 * 5 * 512, 512, 512, 512);
  k_convw<<<gdiv(512ull * 5 * 512), 256, 0, stream>>>(cw4, c4r, 512 * 5 * 512, 512, 512, 512);
  k_convw<<<gdiv(576ull * 5 * 512), 256, 0, stream>>>(cw5, c5r, 576 * 5 * 512, 512, 512, 552);

  // prenet: pre1 = relu(frames@W1^T+b1); C0[t][b][1024:1280] = relu(pre1@W2^T+b2)
  gemm_k<M_RELU><<<dim3(2, 300, 1), 256, 0, stream>>>(frames, pW1b, 576, 576, 256, preb1,
                                                      pre1, 16384, 256, 0, nullptr, nullptr);
  gemm_k<M_RELU><<<dim3(2, 300, 1), 256, 0, stream>>>(pre1, pW2b, 256, 256, 256, preb2,
                                                      C0, 81920, 1280, 1024, nullptr, nullptr);
  // sequential 2-layer LSTM (persistent, 256 blocks, flag-synced groups)
  lstm_k<<<dim3(256), 256, 0, stream>>>(C0, H1, W0c, W1c, bih0, bhh0, bih1, bhh1, flags);
  // zero conv pad rows (X bufs were aliased by C0)
  k_zpad<<<gdiv(64 * 4 * 1600), 256, 0, stream>>>(X0, X1, X2);
  // S_pred = h1 @ linW^T + lin_b ; h1[t*64+b] = H1 + 2*64*1024 offset
  gemm_k<M_LINEAR><<<dim3(5, 300, 1), 256, 0, stream>>>(H1 + 131072, linWb, 1024, 1024, 576, linb,
                                                        nullptr, 0, 0, 0, out, X0);
  // postnet
  gemm_k<M_CONVT><<<dim3(4, 5, 64), 256, 0, stream>>>(X0, c1r, 2880, 576, 512, cb1,
                                                      X1, 0, 0, 0, nullptr, nullptr);
  gemm_k<M_CONVT><<<dim3(4, 5, 64), 256, 0, stream>>>(X1, c2r, 2560, 512, 512, cb2,
                                                      X2, 0, 0, 0, nullptr, nullptr);
  gemm_k<M_CONVT><<<dim3(4, 5, 64), 256, 0, stream>>>(X2, c3r, 2560, 512, 512, cb3,
                                                      X1, 0, 0, 0, nullptr, nullptr);
  gemm_k<M_CONVT><<<dim3(4, 5, 64), 256, 0, stream>>>(X1, c4r, 2560, 512, 512, cb4,
                                                      X2, 0, 0, 0, nullptr, nullptr);
  gemm_k<M_CONVF><<<dim3(5, 5, 64), 256, 0, stream>>>(X2, c5r, 2560, 512, 576, cb5,
                                                      nullptr, 0, 0, 0, out, nullptr);
  (void)in_sizes; (void)n_in; (void)out_size; (void)ws_size;
}

// Round 3
// 5132.718 us; speedup vs baseline: 2.2601x; 1.1798x over previous
//
#include <hip/hip_runtime.h>
#include <cstdint>
#include <cstddef>

typedef __bf16 bf16;
typedef __attribute__((ext_vector_type(8))) __bf16 bf16x8;
typedef __attribute__((ext_vector_type(4))) float f32x4;
typedef __attribute__((ext_vector_type(4))) unsigned u32x4;

#define DEV static __device__ __forceinline__

DEV float sigm_(float x) { return 1.f / (1.f + __expf(-x)); }
DEV float tanhf_(float x) {
  float e = __expf(-2.f * fabsf(x));
  float t = (1.f - e) / (1.f + e);
  return x < 0.f ? -t : t;
}

DEV void gload_lds16(const bf16* g, bf16* l) {
  __builtin_amdgcn_global_load_lds((const __attribute__((address_space(1))) void*)g,
                                   (__attribute__((address_space(3))) void*)l, 16, 0, 0);
}

// ---------------------------------------------------------------------------
// repack kernels
// ---------------------------------------------------------------------------
__global__ void k_frames(const float* __restrict__ S, bf16* __restrict__ dst) {
  int idx = blockIdx.x * 256 + threadIdx.x;
  if (idx >= 38400 * 576) return;
  int r = idx / 576, c = idx - r * 576;
  int t = r >> 6, b = r & 63;
  float v = (t == 0 || c >= 552) ? 0.f : S[((size_t)(t - 1) * 64 + b) * 552 + c];
  dst[idx] = (bf16)v;
}

__global__ void k_pad2d(const float* __restrict__ src, bf16* __restrict__ dst,
                        int N, int Cdst, int Csrc, int Rsrc, int sstride) {
  int idx = blockIdx.x * 256 + threadIdx.x;
  if (idx >= N) return;
  int r = idx / Cdst, c = idx - r * Cdst;
  float v = (r < Rsrc && c < Csrc) ? src[(size_t)r * sstride + c] : 0.f;
  dst[idx] = (bf16)v;
}

__global__ void k_w0c(const float* __restrict__ Whh0, const float* __restrict__ Wih0,
                      bf16* __restrict__ dst) {
  int idx = blockIdx.x * 256 + threadIdx.x;
  if (idx >= 4096 * 1280) return;
  int r = idx / 1280, k = idx - r * 1280;
  float v = (k < 1024) ? Whh0[(size_t)r * 1024 + k] : Wih0[(size_t)r * 384 + (k - 1024)];
  dst[idx] = (bf16)v;
}

__global__ void k_w1c(const float* __restrict__ Wih1, const float* __restrict__ Whh1,
                      bf16* __restrict__ dst) {
  int idx = blockIdx.x * 256 + threadIdx.x;
  if (idx >= 4096 * 2048) return;
  int r = idx / 2048, k = idx - r * 2048;
  float v = (k < 1024) ? Wih1[(size_t)r * 1024 + k] : Whh1[(size_t)r * 1024 + (k - 1024)];
  dst[idx] = (bf16)v;
}

__global__ void k_convw(const float* __restrict__ src, bf16* __restrict__ dst,
                        int N, int Cpad, int Cisrc, int Cosrc) {
  int idx = blockIdx.x * 256 + threadIdx.x;
  if (idx >= N) return;
  int per = 5 * Cpad;
  int co = idx / per, rem = idx - co * per;
  int tap = rem / Cpad, ci = rem - tap * Cpad;
  float v = (co < Cosrc && ci < Cisrc) ? src[((size_t)co * Cisrc + ci) * 5 + tap] : 0.f;
  dst[idx] = (bf16)v;
}

// zero pad rows {0,1,602,603} of X0[64][604][576], X1/X2[64][604][512]
__global__ void k_zpad(bf16* __restrict__ X0, bf16* __restrict__ X1, bf16* __restrict__ X2) {
  int idx = blockIdx.x * 256 + threadIdx.x;
  if (idx >= 64 * 4 * 1600) return;
  int per = 4 * 1600;
  int b = idx / per, rem = idx - b * per;
  int rr = rem / 1600, c = rem - rr * 1600;
  int row = (rr < 2) ? rr : 600 + rr;
  if (c < 576) X0[((size_t)b * 604 + row) * 576 + c] = (bf16)0.f;
  else if (c < 1088) X1[((size_t)b * 604 + row) * 512 + (c - 576)] = (bf16)0.f;
  else X2[((size_t)b * 604 + row) * 512 + (c - 1088)] = (bf16)0.f;
}

// sentinel-poison C0[t][b][0:1024) for t=1..600 (h region only; pre2 cols and
// row 600 pre2 are untouched -- they alias X buffers and must never hold NaN)
__global__ void k_sent(unsigned* __restrict__ C0u) {
  int idx = blockIdx.x * 256 + threadIdx.x;
  if (idx >= 600 * 64 * 512) return;
  int d = idx & 511;
  int rb = idx >> 9;
  int b = rb & 63, t1 = (rb >> 6) + 1;  // rows 1..600
  C0u[(size_t)t1 * 40960 + (size_t)b * 640 + d] = 0xFFFFFFFFu;
}

// ---------------------------------------------------------------------------
// generic NT GEMM (unchanged)
// ---------------------------------------------------------------------------
enum { M_RELU = 0, M_LINEAR = 1, M_CONVT = 2, M_CONVF = 3 };

template <int MODE>
__global__ __launch_bounds__(256) void gemm_k(
    const bf16* __restrict__ A, const bf16* __restrict__ B, int Ktot, int Kstride,
    int Brows, const float* __restrict__ bias,
    bf16* __restrict__ outB, int outStride, int colP, int colOff,
    float* __restrict__ outF, bf16* __restrict__ outX) {
  const int tid = threadIdx.x;
  const int lane = tid & 63, wv = tid >> 6;
  const int n0 = blockIdx.x * 128, m0 = blockIdx.y * 128;
  const int bz = blockIdx.z;
  __shared__ bf16 As[128 * 64];
  __shared__ bf16 Bs[128 * 64];
  f32x4 acc[4][4] = {};
  const int wr = wv >> 1, wc = wv & 1;
  int tap = 0, ci0 = 0;

  for (int kb = 0; kb < Ktot; kb += 64) {
#pragma unroll
    for (int j = 0; j < 4; ++j) {
      int rt = wv * 32 + j * 8 + (lane >> 3);
      const bf16* gp;
      if (MODE == M_CONVT || MODE == M_CONVF) {
        int l = m0 + rt;
        if (l > 599) l = 599;
        gp = A + ((size_t)(bz * 604 + l + tap)) * Kstride + ci0 + (lane & 7) * 8;
      } else {
        gp = A + (size_t)(m0 + rt) * Kstride + kb + (lane & 7) * 8;
      }
      gload_lds16(gp, &As[(wv * 32 + j * 8) * 64]);
    }
#pragma unroll
    for (int j = 0; j < 4; ++j) {
      int rn = n0 + wv * 32 + j * 8 + (lane >> 3);
      if (rn >= Brows) rn = Brows - 1;
      const bf16* gp = B + (size_t)rn * Ktot + kb + (lane & 7) * 8;
      gload_lds16(gp, &Bs[(wv * 32 + j * 8) * 64]);
    }
    __syncthreads();
#pragma unroll
    for (int ks = 0; ks < 2; ++ks) {
      const int ko = ks * 32 + (lane >> 4) * 8;
      bf16x8 af[4], bfr[4];
#pragma unroll
      for (int i = 0; i < 4; ++i) {
        af[i] = *(const bf16x8*)&As[(wr * 64 + i * 16 + (lane & 15)) * 64 + ko];
        bfr[i] = *(const bf16x8*)&Bs[(wc * 64 + i * 16 + (lane & 15)) * 64 + ko];
      }
#pragma unroll
      for (int mi = 0; mi < 4; ++mi)
#pragma unroll
        for (int ni = 0; ni < 4; ++ni)
          acc[mi][ni] = __builtin_amdgcn_mfma_f32_16x16x32_bf16(af[mi], bfr[ni], acc[mi][ni], 0, 0, 0);
    }
    __syncthreads();
    ci0 += 64;
    if (ci0 == Kstride) { ci0 = 0; ++tap; }
  }

  const int r0 = (lane >> 4) * 4, cc = lane & 15;
#pragma unroll
  for (int mi = 0; mi < 4; ++mi) {
#pragma unroll
    for (int ni = 0; ni < 4; ++ni) {
#pragma unroll
      for (int r = 0; r < 4; ++r) {
        float v = acc[mi][ni][r];
        int gr = m0 + wr * 64 + mi * 16 + r0 + r;
        int gc = n0 + wc * 64 + ni * 16 + cc;
        if (MODE == M_RELU) {
          v += bias[gc];
          v = fmaxf(v, 0.f);
          outB[(size_t)(gr >> 6) * outStride + (size_t)(gr & 63) * colP + colOff + gc] = (bf16)v;
        } else if (MODE == M_LINEAR) {
          if (gc < 552) {
            v += bias[gc];
            int t = gr >> 6, b = gr & 63;
            outF[(size_t)gr * 552 + gc] = v;
            outX[((size_t)b * 604 + t + 2) * 576 + gc] = (bf16)v;
          }
        } else if (MODE == M_CONVT) {
          if (gr < 600) {
            v = tanhf_(v + bias[gc]);
            outB[((size_t)bz * 604 + gr + 2) * 512 + gc] = (bf16)v;
          }
        } else {
          if (gr < 600 && gc < 552) {
            v += bias[gc];
            float* p = outF + ((size_t)gr * 64 + bz) * 552 + gc;
            *p += v;
          }
        }
      }
    }
  }
}

// ---------------------------------------------------------------------------
// LSTM scan v6: DATA-AS-FLAG. No flags, no fences, no store drains.
// Valid h = sigm*tanh in (-1,1): bf16 pair 0xFFFFFFFF is unreachable, so h
// regions are pre-poisoned 0xFF and each wave's A-load (global_load_dwordx4
// sc0 sc1: cache-bypass, reads MALL coherence point) doubles as the readiness
// poll: retry while any u32 == 0xFFFFFFFF. Producers fire sc1 8B stores and
// continue -- readiness propagates per-word as a dataflow wavefront instead of
// a per-step max-of-64-producers barrier.
// 512 threads / 8 waves per block; wave w covers k-slice [w*KT/8, ...).
// Gate partials in rotation-swizzled LDS (stride 32, col=(batch+4*unit)&31)
// -> reader conflicts 2-way instead of 16-way. Raw s_barrier + lgkmcnt only
// (never drains vmcnt -> store acks stay off the critical path).
// C0[601][64][1280]: [0:1024)=h0[t-1] (row0=0), [1024:1280)=pre2[t]
// H1[602][64][1024]: h1[t] at row t+2 (rows 0,1 = 0)
// ---------------------------------------------------------------------------
template <int LAYER>
DEV void scan_impl(bf16* __restrict__ C0, bf16* __restrict__ H1,
                   const bf16* __restrict__ W, const float* __restrict__ bi,
                   const float* __restrict__ bh, float* gb, int u0, int b0) {
  constexpr int KT = LAYER ? 2048 : 1280;
  constexpr int NKS = KT / 256;  // per-wave 32-elem chunks: L0=5, L1=8
  const int tid = threadIdx.x, lane = tid & 63, w = tid >> 6;
  const int kb = w * (KT / 8);

  // weight B-fragments -> registers/AGPRs, loaded once
  bf16x8 wreg[4][NKS];
#pragma unroll
  for (int gi = 0; gi < 4; ++gi)
#pragma unroll
    for (int ks = 0; ks < NKS; ++ks)
      wreg[gi][ks] = *(const bf16x8*)(W + (size_t)(gi * 1024 + u0 + (lane & 15)) * KT +
                                      kb + ks * 32 + (lane >> 4) * 8);

  // cell-update mapping: 512 threads = 32 batch x 16 units
  const int uc = tid & 15, bl = tid >> 4;
  float bs[4];
#pragma unroll
  for (int g = 0; g < 4; ++g) bs[g] = bi[g * 1024 + u0 + uc] + bh[g * 1024 + u0 + uc];
  float cst = 0.f;
  const int rotc = (bl + 4 * uc) & 31;  // reader column (rotation swizzle)

  const int r0 = lane & 15, q8 = (lane >> 4) * 8;
  const int un = lane & 15, qb = (lane >> 4) * 4;

  for (int t = 0; t < 600; ++t) {
    // ---- A addresses for this step
    const bf16* A0;
    int RS;
    if (!LAYER) {
      RS = 1280;
      A0 = C0 + (size_t)t * 81920 + (size_t)(b0 + r0) * 1280 + kb + q8;
    } else if (w < 4) {
      RS = 1280;
      A0 = C0 + (size_t)(t + 1) * 81920 + (size_t)(b0 + r0) * 1280 + kb + q8;
    } else {
      RS = 1024;
      A0 = H1 + (size_t)(t + 1) * 65536 + (size_t)(b0 + r0) * 1024 + (kb - 1024) + q8;
    }
    const bf16* A1 = A0 + 16 * RS;

    u32x4 va[NKS], vb[NKS];
    // pre2 chunks (L0 upper-k): plain cached loads, once
    if (!LAYER) {
#pragma unroll
      for (int ks = 0; ks < NKS; ++ks)
        if (kb + ks * 32 >= 1024) {
          va[ks] = *(const u32x4*)(A0 + ks * 32);
          vb[ks] = *(const u32x4*)(A1 + ks * 32);
        }
    }
    // ---- poll-load h chunks (the load IS the readiness check)
    for (;;) {
#pragma unroll
      for (int ks = 0; ks < NKS; ++ks) {
        if (LAYER || kb + ks * 32 < 1024) {
          asm volatile("global_load_dwordx4 %0, %1, off sc0 sc1"
                       : "=v"(va[ks]) : "v"(A0 + ks * 32) : "memory");
          asm volatile("global_load_dwordx4 %0, %1, off sc0 sc1"
                       : "=v"(vb[ks]) : "v"(A1 + ks * 32) : "memory");
        }
      }
      asm volatile("s_waitcnt vmcnt(0)" ::: "memory");
      __builtin_amdgcn_sched_barrier(0);
      unsigned bad = 0;
#pragma unroll
      for (int ks = 0; ks < NKS; ++ks) {
        if (LAYER || kb + ks * 32 < 1024) {
          bad |= (va[ks].x == 0xFFFFFFFFu) | (va[ks].y == 0xFFFFFFFFu) |
                 (va[ks].z == 0xFFFFFFFFu) | (va[ks].w == 0xFFFFFFFFu) |
                 (vb[ks].x == 0xFFFFFFFFu) | (vb[ks].y == 0xFFFFFFFFu) |
                 (vb[ks].z == 0xFFFFFFFFu) | (vb[ks].w == 0xFFFFFFFFu);
        }
      }
      if (!__ballot(bad)) break;
      __builtin_amdgcn_s_sleep(2);
    }

    // ---- MFMA accumulate over this wave's k-slice
    f32x4 acc[4][2] = {};
#pragma unroll
    for (int ks = 0; ks < NKS; ++ks) {
      bf16x8 a0 = *(const bf16x8*)&va[ks];
      bf16x8 a1 = *(const bf16x8*)&vb[ks];
#pragma unroll
      for (int gi = 0; gi < 4; ++gi) {
        acc[gi][0] = __builtin_amdgcn_mfma_f32_16x16x32_bf16(a0, wreg[gi][ks], acc[gi][0], 0, 0, 0);
        acc[gi][1] = __builtin_amdgcn_mfma_f32_16x16x32_bf16(a1, wreg[gi][ks], acc[gi][1], 0, 0, 0);
      }
    }

    // ---- k-partials to LDS: row=(w*4+gi)*16+unit, rotated col (conflict-free)
#pragma unroll
    for (int gi = 0; gi < 4; ++gi)
#pragma unroll
      for (int b2 = 0; b2 < 2; ++b2)
        *(f32x4*)&gb[((w * 4 + gi) * 16 + un) * 32 + ((b2 * 16 + qb + 4 * un) & 31)] = acc[gi][b2];

    asm volatile("s_waitcnt lgkmcnt(0)" ::: "memory");
    __builtin_amdgcn_s_barrier();
    __builtin_amdgcn_sched_barrier(0);

    // ---- cell update: thread = (batch bl, unit uc), c in regs
    float s4[4];
#pragma unroll
    for (int g = 0; g < 4; ++g) {
      float a = 0.f;
#pragma unroll
      for (int ww = 0; ww < 8; ++ww) a += gb[((ww * 4 + g) * 16 + uc) * 32 + rotc];
      s4[g] = a + bs[g];
    }
    float c = sigm_(s4[1]) * cst + sigm_(s4[0]) * tanhf_(s4[2]);
    cst = c;
    float h = sigm_(s4[3]) * tanhf_(c);

    // ---- pack 4 units -> 8B, store sc1 (no drain, no flag)
    float h1 = __shfl_down(h, 1), h2 = __shfl_down(h, 2), h3 = __shfl_down(h, 3);
    if ((uc & 3) == 0) {
      union { bf16 q[4]; unsigned long long u; } pk;
      pk.q[0] = (bf16)h; pk.q[1] = (bf16)h1; pk.q[2] = (bf16)h2; pk.q[3] = (bf16)h3;
      unsigned long long* dst = LAYER
          ? (unsigned long long*)(H1 + (size_t)(t + 2) * 65536 + (size_t)(b0 + bl) * 1024 + u0 + uc)
          : (unsigned long long*)(C0 + (size_t)(t + 1) * 81920 + (size_t)(b0 + bl) * 1280 + u0 + uc);
      __hip_atomic_store(dst, pk.u, __ATOMIC_RELAXED, __HIP_MEMORY_SCOPE_AGENT);
    }

    asm volatile("s_waitcnt lgkmcnt(0)" ::: "memory");
    __builtin_amdgcn_s_barrier();
    __builtin_amdgcn_sched_barrier(0);
  }
}

__global__ __launch_bounds__(512, 1) void lstm_k(
    bf16* __restrict__ C0, bf16* __restrict__ H1,
    const bf16* __restrict__ W0, const bf16* __restrict__ W1,
    const float* __restrict__ bi0, const float* __restrict__ bh0,
    const float* __restrict__ bi1, const float* __restrict__ bh1) {
  __shared__ float gb[512 * 32];  // 64 KB gate partials (rotation-swizzled)
  const int bid = blockIdx.x;
  const int layer = bid >> 7, sub = bid & 127;
  const int mh = sub >> 6, ub = sub & 63;
  const int u0 = ub * 16, b0 = mh * 32;
  if (layer == 0)
    scan_impl<0>(C0, H1, W0, bi0, bh0, gb, u0, b0);
  else
    scan_impl<1>(C0, H1, W1, bi1, bh1, gb, u0, b0);
}

// ---------------------------------------------------------------------------
// host
// ---------------------------------------------------------------------------
static inline unsigned gdiv(size_t n) { return (unsigned)((n + 255) / 256); }

extern "C" void kernel_launch(void* const* d_in, const int* in_sizes, int n_in,
                              void* d_out, int out_size, void* d_ws, size_t ws_size,
                              hipStream_t stream) {
  const float* S = (const float*)d_in[0];
  const float* preW1 = (const float*)d_in[1];
  const float* preb1 = (const float*)d_in[2];
  const float* preW2 = (const float*)d_in[3];
  const float* preb2 = (const float*)d_in[4];
  const float* Wih0 = (const float*)d_in[5];
  const float* Whh0 = (const float*)d_in[6];
  const float* bih0 = (const float*)d_in[7];
  const float* bhh0 = (const float*)d_in[8];
  const float* Wih1 = (const float*)d_in[9];
  const float* Whh1 = (const float*)d_in[10];
  const float* bih1 = (const float*)d_in[11];
  const float* bhh1 = (const float*)d_in[12];
  const float* linW = (const float*)d_in[13];
  const float* linb = (const float*)d_in[14];
  const float* cw1 = (const float*)d_in[15];
  const float* cb1 = (const float*)d_in[16];
  const float* cw2 = (const float*)d_in[17];
  const float* cb2 = (const float*)d_in[18];
  const float* cw3 = (const float*)d_in[19];
  const float* cb3 = (const float*)d_in[20];
  const float* cw4 = (const float*)d_in[21];
  const float* cb4 = (const float*)d_in[22];
  const float* cw5 = (const float*)d_in[23];
  const float* cb5 = (const float*)d_in[24];
  float* out = (float*)d_out;

  char* ws = (char*)d_ws;
  size_t off = 0;
  auto alloc = [&](size_t bytes) -> char* {
    char* p = ws + off;
    off += (bytes + 255) & ~(size_t)255;
    return p;
  };
  bf16* H1 = (bf16*)alloc(602ull * 64 * 1024 * 2);
  bf16* frames = (bf16*)alloc(38400ull * 576 * 2);
  bf16* pre1 = (bf16*)alloc(38400ull * 256 * 2);
  bf16* W0c = (bf16*)alloc(4096ull * 1280 * 2);
  bf16* W1c = (bf16*)alloc(4096ull * 2048 * 2);
  bf16* pW1b = (bf16*)alloc(256ull * 576 * 2);
  bf16* pW2b = (bf16*)alloc(256ull * 256 * 2);
  bf16* linWb = (bf16*)alloc(576ull * 1024 * 2);
  bf16* c1r = (bf16*)alloc(512ull * 5 * 576 * 2);
  bf16* c2r = (bf16*)alloc(512ull * 5 * 512 * 2);
  bf16* c3r = (bf16*)alloc(512ull * 5 * 512 * 2);
  bf16* c4r = (bf16*)alloc(512ull * 5 * 512 * 2);
  bf16* c5r = (bf16*)alloc(576ull * 5 * 512 * 2);
  bf16* X0 = (bf16*)alloc(64ull * 604 * 576 * 2);
  bf16* X1 = (bf16*)alloc(64ull * 604 * 512 * 2);
  bf16* X2 = (bf16*)alloc(64ull * 604 * 512 * 2);
  bf16* C0 = X0;  // C0[601][64][1280] aliases X0..X2 (dead until after lstm)

  // H1 rows 0,1 = 0; H1 rows 2..601 = sentinel 0xFF; C0 row 0 = 0
  hipMemsetAsync(H1, 0, 2ull * 64 * 1024 * 2, stream);
  hipMemsetAsync((char*)H1 + 2ull * 64 * 1024 * 2, 0xFF, 600ull * 64 * 1024 * 2, stream);
  hipMemsetAsync(C0, 0, 64ull * 1280 * 2, stream);
  // C0 rows 1..600 h-cols = sentinel (pre2 cols untouched)
  k_sent<<<gdiv(600ull * 64 * 512), 256, 0, stream>>>((unsigned*)C0);

  // repacks
  k_frames<<<gdiv(38400ull * 576), 256, 0, stream>>>(S, frames);
  k_pad2d<<<gdiv(256 * 576), 256, 0, stream>>>(preW1, pW1b, 256 * 576, 576, 552, 256, 552);
  k_pad2d<<<gdiv(256 * 256), 256, 0, stream>>>(preW2, pW2b, 256 * 256, 256, 256, 256, 256);
  k_pad2d<<<gdiv(576 * 1024), 256, 0, stream>>>(linW, linWb, 576 * 1024, 1024, 1024, 552, 1152);
  k_w0c<<<gdiv(4096ull * 1280), 256, 0, stream>>>(Whh0, Wih0, W0c);
  k_w1c<<<gdiv(4096ull * 2048), 256, 0, stream>>>(Wih1, Whh1, W1c);
  k_convw<<<gdiv(512ull * 5 * 576), 256, 0, stream>>>(cw1, c1r, 512 * 5 * 576, 576, 552, 512);
  k_convw<<<gdiv(512ull * 5 * 512), 256, 0, stream>>>(cw2, c2r, 512 * 5 * 512, 512, 512, 512);
  k_convw<<<gdiv(512ull * 5 * 512), 256, 0, stream>>>(cw3, c3r, 512 * 5 * 512, 512, 512, 512);
  k_convw<<<gdiv(512ull * 5 * 512), 256, 0, stream>>>(cw4, c4r, 512 * 5 * 512, 512, 512, 512);
  k_convw<<<gdiv(576ull * 5 * 512), 256, 0, stream>>>(cw5, c5r, 576 * 5 * 512, 512, 512, 552);

  // prenet: pre1 = relu(frames@W1^T+b1); C0[t][b][1024:1280] = relu(pre1@W2^T+b2)
  gemm_k<M_RELU><<<dim3(2, 300, 1), 256, 0, stream>>>(frames, pW1b, 576, 576, 256, preb1,
                                                      pre1, 16384, 256, 0, nullptr, nullptr);
  gemm_k<M_RELU><<<dim3(2, 300, 1), 256, 0, stream>>>(pre1, pW2b, 256, 256, 256, preb2,
                                                      C0, 81920, 1280, 1024, nullptr, nullptr);
  // sequential 2-layer LSTM (persistent, 256 blocks x 512 thr, data-as-flag)
  lstm_k<<<dim3(256), 512, 0, stream>>>(C0, H1, W0c, W1c, bih0, bhh0, bih1, bhh1);
  // zero conv pad rows (X bufs were aliased by C0)
  k_zpad<<<gdiv(64 * 4 * 1600), 256, 0, stream>>>(X0, X1, X2);
  // S_pred = h1 @ linW^T + lin_b ; h1[t*64+b] = H1 + 2*64*1024 offset
  gemm_k<M_LINEAR><<<dim3(5, 300, 1), 256, 0, stream>>>(H1 + 131072, linWb, 1024, 1024, 576, linb,
                                                        nullptr, 0, 0, 0, out, X0);
  // postnet
  gemm_k<M_CONVT><<<dim3(4, 5, 64), 256, 0, stream>>>(X0, c1r, 2880, 576, 512, cb1,
                                                      X1, 0, 0, 0, nullptr, nullptr);
  gemm_k<M_CONVT><<<dim3(4, 5, 64), 256, 0, stream>>>(X1, c2r, 2560, 512, 512, cb2,
                                                      X2, 0, 0, 0, nullptr, nullptr);
  gemm_k<M_CONVT><<<dim3(4, 5, 64), 256, 0, stream>>>(X2, c3r, 2560, 512, 512, cb3,
                                                      X1, 0, 0, 0, nullptr, nullptr);
  gemm_k<M_CONVT><<<dim3(4, 5, 64), 256, 0, stream>>>(X1, c4r, 2560, 512, 512, cb4,
                                                      X2, 0, 0, 0, nullptr, nullptr);
  gemm_k<M_CONVF><<<dim3(5, 5, 64), 256, 0, stream>>>(X2, c5r, 2560, 512, 576, cb5,
                                                      nullptr, 0, 0, 0, out, nullptr);
  (void)in_sizes; (void)n_in; (void)out_size; (void)ws_size;
}

// Round 4
// 4978.487 us; speedup vs baseline: 2.3301x; 1.0310x over previous
//
#include <hip/hip_runtime.h>
#include <cstdint>
#include <cstddef>

typedef __bf16 bf16;
typedef __attribute__((ext_vector_type(8))) __bf16 bf16x8;
typedef __attribute__((ext_vector_type(4))) float f32x4;
typedef __attribute__((ext_vector_type(4))) unsigned u32x4;

#define DEV static __device__ __forceinline__

DEV float sigm_(float x) { return 1.f / (1.f + __expf(-x)); }
DEV float tanhf_(float x) {
  float e = __expf(-2.f * fabsf(x));
  float t = (1.f - e) / (1.f + e);
  return x < 0.f ? -t : t;
}

DEV void gload_lds16(const bf16* g, bf16* l) {
  __builtin_amdgcn_global_load_lds((const __attribute__((address_space(1))) void*)g,
                                   (__attribute__((address_space(3))) void*)l, 16, 0, 0);
}

// ---------------------------------------------------------------------------
// repack kernels
// ---------------------------------------------------------------------------
__global__ void k_frames(const float* __restrict__ S, bf16* __restrict__ dst) {
  int idx = blockIdx.x * 256 + threadIdx.x;
  if (idx >= 38400 * 576) return;
  int r = idx / 576, c = idx - r * 576;
  int t = r >> 6, b = r & 63;
  float v = (t == 0 || c >= 552) ? 0.f : S[((size_t)(t - 1) * 64 + b) * 552 + c];
  dst[idx] = (bf16)v;
}

__global__ void k_pad2d(const float* __restrict__ src, bf16* __restrict__ dst,
                        int N, int Cdst, int Csrc, int Rsrc, int sstride) {
  int idx = blockIdx.x * 256 + threadIdx.x;
  if (idx >= N) return;
  int r = idx / Cdst, c = idx - r * Cdst;
  float v = (r < Rsrc && c < Csrc) ? src[(size_t)r * sstride + c] : 0.f;
  dst[idx] = (bf16)v;
}

__global__ void k_w0c(const float* __restrict__ Whh0, const float* __restrict__ Wih0,
                      bf16* __restrict__ dst) {
  int idx = blockIdx.x * 256 + threadIdx.x;
  if (idx >= 4096 * 1280) return;
  int r = idx / 1280, k = idx - r * 1280;
  float v = (k < 1024) ? Whh0[(size_t)r * 1024 + k] : Wih0[(size_t)r * 384 + (k - 1024)];
  dst[idx] = (bf16)v;
}

__global__ void k_w1c(const float* __restrict__ Wih1, const float* __restrict__ Whh1,
                      bf16* __restrict__ dst) {
  int idx = blockIdx.x * 256 + threadIdx.x;
  if (idx >= 4096 * 2048) return;
  int r = idx / 2048, k = idx - r * 2048;
  float v = (k < 1024) ? Wih1[(size_t)r * 1024 + k] : Whh1[(size_t)r * 1024 + (k - 1024)];
  dst[idx] = (bf16)v;
}

__global__ void k_convw(const float* __restrict__ src, bf16* __restrict__ dst,
                        int N, int Cpad, int Cisrc, int Cosrc) {
  int idx = blockIdx.x * 256 + threadIdx.x;
  if (idx >= N) return;
  int per = 5 * Cpad;
  int co = idx / per, rem = idx - co * per;
  int tap = rem / Cpad, ci = rem - tap * Cpad;
  float v = (co < Cosrc && ci < Cisrc) ? src[((size_t)co * Cisrc + ci) * 5 + tap] : 0.f;
  dst[idx] = (bf16)v;
}

// zero pad rows {0,1,602,603} of X0[64][604][576], X1/X2[64][604][512]
__global__ void k_zpad(bf16* __restrict__ X0, bf16* __restrict__ X1, bf16* __restrict__ X2) {
  int idx = blockIdx.x * 256 + threadIdx.x;
  if (idx >= 64 * 4 * 1600) return;
  int per = 4 * 1600;
  int b = idx / per, rem = idx - b * per;
  int rr = rem / 1600, c = rem - rr * 1600;
  int row = (rr < 2) ? rr : 600 + rr;
  if (c < 576) X0[((size_t)b * 604 + row) * 576 + c] = (bf16)0.f;
  else if (c < 1088) X1[((size_t)b * 604 + row) * 512 + (c - 576)] = (bf16)0.f;
  else X2[((size_t)b * 604 + row) * 512 + (c - 1088)] = (bf16)0.f;
}

// ---------------------------------------------------------------------------
// generic NT GEMM (unchanged)
// ---------------------------------------------------------------------------
enum { M_RELU = 0, M_LINEAR = 1, M_CONVT = 2, M_CONVF = 3 };

template <int MODE>
__global__ __launch_bounds__(256) void gemm_k(
    const bf16* __restrict__ A, const bf16* __restrict__ B, int Ktot, int Kstride,
    int Brows, const float* __restrict__ bias,
    bf16* __restrict__ outB, int outStride, int colP, int colOff,
    float* __restrict__ outF, bf16* __restrict__ outX) {
  const int tid = threadIdx.x;
  const int lane = tid & 63, wv = tid >> 6;
  const int n0 = blockIdx.x * 128, m0 = blockIdx.y * 128;
  const int bz = blockIdx.z;
  __shared__ bf16 As[128 * 64];
  __shared__ bf16 Bs[128 * 64];
  f32x4 acc[4][4] = {};
  const int wr = wv >> 1, wc = wv & 1;
  int tap = 0, ci0 = 0;

  for (int kb = 0; kb < Ktot; kb += 64) {
#pragma unroll
    for (int j = 0; j < 4; ++j) {
      int rt = wv * 32 + j * 8 + (lane >> 3);
      const bf16* gp;
      if (MODE == M_CONVT || MODE == M_CONVF) {
        int l = m0 + rt;
        if (l > 599) l = 599;
        gp = A + ((size_t)(bz * 604 + l + tap)) * Kstride + ci0 + (lane & 7) * 8;
      } else {
        gp = A + (size_t)(m0 + rt) * Kstride + kb + (lane & 7) * 8;
      }
      gload_lds16(gp, &As[(wv * 32 + j * 8) * 64]);
    }
#pragma unroll
    for (int j = 0; j < 4; ++j) {
      int rn = n0 + wv * 32 + j * 8 + (lane >> 3);
      if (rn >= Brows) rn = Brows - 1;
      const bf16* gp = B + (size_t)rn * Ktot + kb + (lane & 7) * 8;
      gload_lds16(gp, &Bs[(wv * 32 + j * 8) * 64]);
    }
    __syncthreads();
#pragma unroll
    for (int ks = 0; ks < 2; ++ks) {
      const int ko = ks * 32 + (lane >> 4) * 8;
      bf16x8 af[4], bfr[4];
#pragma unroll
      for (int i = 0; i < 4; ++i) {
        af[i] = *(const bf16x8*)&As[(wr * 64 + i * 16 + (lane & 15)) * 64 + ko];
        bfr[i] = *(const bf16x8*)&Bs[(wc * 64 + i * 16 + (lane & 15)) * 64 + ko];
      }
#pragma unroll
      for (int mi = 0; mi < 4; ++mi)
#pragma unroll
        for (int ni = 0; ni < 4; ++ni)
          acc[mi][ni] = __builtin_amdgcn_mfma_f32_16x16x32_bf16(af[mi], bfr[ni], acc[mi][ni], 0, 0, 0);
    }
    __syncthreads();
    ci0 += 64;
    if (ci0 == Kstride) { ci0 = 0; ++tap; }
  }

  const int r0 = (lane >> 4) * 4, cc = lane & 15;
#pragma unroll
  for (int mi = 0; mi < 4; ++mi) {
#pragma unroll
    for (int ni = 0; ni < 4; ++ni) {
#pragma unroll
      for (int r = 0; r < 4; ++r) {
        float v = acc[mi][ni][r];
        int gr = m0 + wr * 64 + mi * 16 + r0 + r;
        int gc = n0 + wc * 64 + ni * 16 + cc;
        if (MODE == M_RELU) {
          v += bias[gc];
          v = fmaxf(v, 0.f);
          outB[(size_t)(gr >> 6) * outStride + (size_t)(gr & 63) * colP + colOff + gc] = (bf16)v;
        } else if (MODE == M_LINEAR) {
          if (gc < 552) {
            v += bias[gc];
            int t = gr >> 6, b = gr & 63;
            outF[(size_t)gr * 552 + gc] = v;
            outX[((size_t)b * 604 + t + 2) * 576 + gc] = (bf16)v;
          }
        } else if (MODE == M_CONVT) {
          if (gr < 600) {
            v = tanhf_(v + bias[gc]);
            outB[((size_t)bz * 604 + gr + 2) * 512 + gc] = (bf16)v;
          }
        } else {
          if (gr < 600 && gc < 552) {
            v += bias[gc];
            float* p = outF + ((size_t)gr * 64 + bz) * 552 + gc;
            *p += v;
          }
        }
      }
    }
  }
}

// ---------------------------------------------------------------------------
// LSTM scan v7: per-wave fine-grained FLAG polls (tiny bypass loads) +
// CACHED bulk A-loads (L2-dedup'd across the 8 blocks/XCD sharing a panel).
// Combines v5's validated no-fence cached-load publish protocol
// (h sc1 stores -> own vmcnt(0) -> barrier -> flag) with v6's per-wave
// dataflow waits (each wave polls only the <=16 producers covering its
// k-slice; L0 wave 7 reads pure pre2 and never waits). No fences anywhere:
// inter-block data is write-once (sc1 write-through, drained before flag),
// consumers touch fresh addresses each step -> no stale lines possible.
// 512 threads / 8 waves; wave w covers k-slice [w*KT/8, (w+1)*KT/8).
// Gate partials in rotation-swizzled LDS (stride 32, col=(batch+4*unit)&31).
// C0[601][64][1280]: [0:1024)=h0[t-1] (row0=0), [1024:1280)=pre2[t]
// H1[602][64][1024]: h1[t] at row t+2 (rows 0,1 = 0)
// flags[g][i] at (g*64+i)*32 u32 (128B pad), g = layer*2 + mh.
// ---------------------------------------------------------------------------
template <int LAYER>
DEV void scan_impl(bf16* __restrict__ C0, bf16* __restrict__ H1,
                   const bf16* __restrict__ W, const float* __restrict__ bi,
                   const float* __restrict__ bh, unsigned* __restrict__ flags,
                   float* gb, int u0, int b0, int mh, int ub) {
  constexpr int KT = LAYER ? 2048 : 1280;
  constexpr int NKS = KT / 256;  // per-wave 32-elem chunks: L0=5, L1=8
  const int tid = threadIdx.x, lane = tid & 63, w = tid >> 6;
  const int kb = w * (KT / 8);

  // weight B-fragments -> registers/AGPRs, loaded once
  bf16x8 wreg[4][NKS];
#pragma unroll
  for (int gi = 0; gi < 4; ++gi)
#pragma unroll
    for (int ks = 0; ks < NKS; ++ks)
      wreg[gi][ks] = *(const bf16x8*)(W + (size_t)(gi * 1024 + u0 + (lane & 15)) * KT +
                                      kb + ks * 32 + (lane >> 4) * 8);

  // cell-update mapping: 512 threads = 32 batch x 16 units
  const int uc = tid & 15, bl = tid >> 4;
  float bs[4];
#pragma unroll
  for (int g = 0; g < 4; ++g) bs[g] = bi[g * 1024 + u0 + uc] + bh[g * 1024 + u0 + uc];
  float cst = 0.f;
  const int rotc = (bl + 4 * uc) & 31;  // reader column (rotation swizzle)

  unsigned* flO = flags + (LAYER * 2 + mh) * 64 * 32;  // own group
  unsigned* flP = flags + mh * 64 * 32;                // L0 group, same batch half

  // per-wave producer-flag slice covering this wave's k columns
  const unsigned* fl;
  int fb, nf, thrAdd;
  if (!LAYER) {
    // wave w: cols [160w,160w+160) -> h units -> ub [10w, ...): w<6 ->10,
    // w==6 -> ubs 60..63 (4), w==7 pure pre2 -> no wait
    fl = flO; fb = w * 10; nf = (w < 6) ? 10 : (w == 6 ? 4 : 0); thrAdd = 0;
  } else if (w < 4) {
    // h0[t] cols [256w,+256) -> L0-group ub [16w,+16), flag >= t+1
    fl = flP; fb = w * 16; nf = 16; thrAdd = 1;
  } else {
    // h1[t-1] cols -> own-group ub [16(w-4),+16), flag >= t
    fl = flO; fb = (w - 4) * 16; nf = 16; thrAdd = 0;
  }

  const int r0 = lane & 15, q8 = (lane >> 4) * 8;
  const int un = lane & 15, qb = (lane >> 4) * 4;

  for (int t = 0; t < 600; ++t) {
    // ---- per-wave wait: only this wave's k-slice producers (tiny bypass polls)
    if (nf && (LAYER || t > 0)) {
      const unsigned thr = (unsigned)(t + thrAdd);
      for (;;) {
        unsigned f = (lane < nf)
            ? __hip_atomic_load(&fl[(fb + lane) << 5], __ATOMIC_RELAXED, __HIP_MEMORY_SCOPE_AGENT)
            : 0xFFFFFFFFu;
        if (!__ballot(f < thr)) break;
        __builtin_amdgcn_s_sleep(1);
      }
      __builtin_amdgcn_sched_barrier(0);
      asm volatile("" ::: "memory");  // keep A-loads below the poll
    }

    // ---- A fragments: plain cached loads (L2-dedup across blocks on XCD)
    const bf16* A0;
    int RS;
    if (!LAYER) {
      RS = 1280;
      A0 = C0 + (size_t)t * 81920 + (size_t)(b0 + r0) * 1280 + kb + q8;
    } else if (w < 4) {
      RS = 1280;
      A0 = C0 + (size_t)(t + 1) * 81920 + (size_t)(b0 + r0) * 1280 + kb + q8;
    } else {
      RS = 1024;
      A0 = H1 + (size_t)(t + 1) * 65536 + (size_t)(b0 + r0) * 1024 + (kb - 1024) + q8;
    }
    const bf16* A1 = A0 + 16 * RS;

    f32x4 acc[4][2] = {};
#pragma unroll
    for (int ks = 0; ks < NKS; ++ks) {
      bf16x8 a0 = *(const bf16x8*)(A0 + ks * 32);
      bf16x8 a1 = *(const bf16x8*)(A1 + ks * 32);
#pragma unroll
      for (int gi = 0; gi < 4; ++gi) {
        acc[gi][0] = __builtin_amdgcn_mfma_f32_16x16x32_bf16(a0, wreg[gi][ks], acc[gi][0], 0, 0, 0);
        acc[gi][1] = __builtin_amdgcn_mfma_f32_16x16x32_bf16(a1, wreg[gi][ks], acc[gi][1], 0, 0, 0);
      }
    }

    // ---- k-partials to LDS: row=(w*4+gi)*16+unit, rotated col
#pragma unroll
    for (int gi = 0; gi < 4; ++gi)
#pragma unroll
      for (int b2 = 0; b2 < 2; ++b2)
        *(f32x4*)&gb[((w * 4 + gi) * 16 + un) * 32 + ((b2 * 16 + qb + 4 * un) & 31)] = acc[gi][b2];

    asm volatile("s_waitcnt lgkmcnt(0)" ::: "memory");
    __builtin_amdgcn_s_barrier();
    __builtin_amdgcn_sched_barrier(0);

    // ---- cell update: thread = (batch bl, unit uc), c in regs
    float s4[4];
#pragma unroll
    for (int g = 0; g < 4; ++g) {
      float a = 0.f;
#pragma unroll
      for (int ww = 0; ww < 8; ++ww) a += gb[((ww * 4 + g) * 16 + uc) * 32 + rotc];
      s4[g] = a + bs[g];
    }
    float c = sigm_(s4[1]) * cst + sigm_(s4[0]) * tanhf_(s4[2]);
    cst = c;
    float h = sigm_(s4[3]) * tanhf_(c);

    // ---- pack 4 units -> 8B sc1 store
    float h1 = __shfl_down(h, 1), h2 = __shfl_down(h, 2), h3 = __shfl_down(h, 3);
    if ((uc & 3) == 0) {
      union { bf16 q[4]; unsigned long long u; } pk;
      pk.q[0] = (bf16)h; pk.q[1] = (bf16)h1; pk.q[2] = (bf16)h2; pk.q[3] = (bf16)h3;
      unsigned long long* dst = LAYER
          ? (unsigned long long*)(H1 + (size_t)(t + 2) * 65536 + (size_t)(b0 + bl) * 1024 + u0 + uc)
          : (unsigned long long*)(C0 + (size_t)(t + 1) * 81920 + (size_t)(b0 + bl) * 1280 + u0 + uc);
      __hip_atomic_store(dst, pk.u, __ATOMIC_RELAXED, __HIP_MEMORY_SCOPE_AGENT);
    }
    asm volatile("s_waitcnt vmcnt(0)" ::: "memory");  // own h-stores at coherence point
    __builtin_amdgcn_s_barrier();                      // all block's h-stores done
    __builtin_amdgcn_sched_barrier(0);
    if (tid == 0)
      __hip_atomic_store(&flO[ub << 5], (unsigned)(t + 1), __ATOMIC_RELAXED, __HIP_MEMORY_SCOPE_AGENT);
  }
}

__global__ __launch_bounds__(512, 1) void lstm_k(
    bf16* __restrict__ C0, bf16* __restrict__ H1,
    const bf16* __restrict__ W0, const bf16* __restrict__ W1,
    const float* __restrict__ bi0, const float* __restrict__ bh0,
    const float* __restrict__ bi1, const float* __restrict__ bh1,
    unsigned* __restrict__ flags) {
  __shared__ float gb[512 * 32];  // 64 KB gate partials (rotation-swizzled)
  const int bid = blockIdx.x;
  const int layer = bid >> 7, sub = bid & 127;
  const int mh = sub >> 6, ub = sub & 63;
  const int u0 = ub * 16, b0 = mh * 32;
  if (layer == 0)
    scan_impl<0>(C0, H1, W0, bi0, bh0, flags, gb, u0, b0, mh, ub);
  else
    scan_impl<1>(C0, H1, W1, bi1, bh1, flags, gb, u0, b0, mh, ub);
}

// ---------------------------------------------------------------------------
// host
// ---------------------------------------------------------------------------
static inline unsigned gdiv(size_t n) { return (unsigned)((n + 255) / 256); }

extern "C" void kernel_launch(void* const* d_in, const int* in_sizes, int n_in,
                              void* d_out, int out_size, void* d_ws, size_t ws_size,
                              hipStream_t stream) {
  const float* S = (const float*)d_in[0];
  const float* preW1 = (const float*)d_in[1];
  const float* preb1 = (const float*)d_in[2];
  const float* preW2 = (const float*)d_in[3];
  const float* preb2 = (const float*)d_in[4];
  const float* Wih0 = (const float*)d_in[5];
  const float* Whh0 = (const float*)d_in[6];
  const float* bih0 = (const float*)d_in[7];
  const float* bhh0 = (const float*)d_in[8];
  const float* Wih1 = (const float*)d_in[9];
  const float* Whh1 = (const float*)d_in[10];
  const float* bih1 = (const float*)d_in[11];
  const float* bhh1 = (const float*)d_in[12];
  const float* linW = (const float*)d_in[13];
  const float* linb = (const float*)d_in[14];
  const float* cw1 = (const float*)d_in[15];
  const float* cb1 = (const float*)d_in[16];
  const float* cw2 = (const float*)d_in[17];
  const float* cb2 = (const float*)d_in[18];
  const float* cw3 = (const float*)d_in[19];
  const float* cb3 = (const float*)d_in[20];
  const float* cw4 = (const float*)d_in[21];
  const float* cb4 = (const float*)d_in[22];
  const float* cw5 = (const float*)d_in[23];
  const float* cb5 = (const float*)d_in[24];
  float* out = (float*)d_out;

  char* ws = (char*)d_ws;
  size_t off = 0;
  auto alloc = [&](size_t bytes) -> char* {
    char* p = ws + off;
    off += (bytes + 255) & ~(size_t)255;
    return p;
  };
  unsigned* flags = (unsigned*)alloc(32768);  // 4 groups x 64 flags x 128B pad
  bf16* H1 = (bf16*)alloc(602ull * 64 * 1024 * 2);
  bf16* frames = (bf16*)alloc(38400ull * 576 * 2);
  bf16* pre1 = (bf16*)alloc(38400ull * 256 * 2);
  bf16* W0c = (bf16*)alloc(4096ull * 1280 * 2);
  bf16* W1c = (bf16*)alloc(4096ull * 2048 * 2);
  bf16* pW1b = (bf16*)alloc(256ull * 576 * 2);
  bf16* pW2b = (bf16*)alloc(256ull * 256 * 2);
  bf16* linWb = (bf16*)alloc(576ull * 1024 * 2);
  bf16* c1r = (bf16*)alloc(512ull * 5 * 576 * 2);
  bf16* c2r = (bf16*)alloc(512ull * 5 * 512 * 2);
  bf16* c3r = (bf16*)alloc(512ull * 5 * 512 * 2);
  bf16* c4r = (bf16*)alloc(512ull * 5 * 512 * 2);
  bf16* c5r = (bf16*)alloc(576ull * 5 * 512 * 2);
  bf16* X0 = (bf16*)alloc(64ull * 604 * 576 * 2);
  bf16* X1 = (bf16*)alloc(64ull * 604 * 512 * 2);
  bf16* X2 = (bf16*)alloc(64ull * 604 * 512 * 2);
  bf16* C0 = X0;  // C0[601][64][1280] aliases X0..X2 (dead until after lstm)

  // zero: flags + H1 rows 0,1 (contiguous after flags) ; C0 row 0
  hipMemsetAsync(ws, 0, 32768 + 2ull * 64 * 1024 * 2, stream);
  hipMemsetAsync(C0, 0, 64ull * 1280 * 2, stream);

  // repacks
  k_frames<<<gdiv(38400ull * 576), 256, 0, stream>>>(S, frames);
  k_pad2d<<<gdiv(256 * 576), 256, 0, stream>>>(preW1, pW1b, 256 * 576, 576, 552, 256, 552);
  k_pad2d<<<gdiv(256 * 256), 256, 0, stream>>>(preW2, pW2b, 256 * 256, 256, 256, 256, 256);
  k_pad2d<<<gdiv(576 * 1024), 256, 0, stream>>>(linW, linWb, 576 * 1024, 1024, 1024, 552, 1152);
  k_w0c<<<gdiv(4096ull * 1280), 256, 0, stream>>>(Whh0, Wih0, W0c);
  k_w1c<<<gdiv(4096ull * 2048), 256, 0, stream>>>(Wih1, Whh1, W1c);
  k_convw<<<gdiv(512ull * 5 * 576), 256, 0, stream>>>(cw1, c1r, 512 * 5 * 576, 576, 552, 512);
  k_convw<<<gdiv(512ull * 5 * 512), 256, 0, stream>>>(cw2, c2r, 512 * 5 * 512, 512, 512, 512);
  k_convw<<<gdiv(512ull * 5 * 512), 256, 0, stream>>>(cw3, c3r, 512 * 5 * 512, 512, 512, 512);
  k_convw<<<gdiv(512ull * 5 * 512), 256, 0, stream>>>(cw4, c4r, 512 * 5 * 512, 512, 512, 512);
  k_convw<<<gdiv(576ull * 5 * 512), 256, 0, stream>>>(cw5, c5r, 576 * 5 * 512, 512, 512, 552);

  // prenet: pre1 = relu(frames@W1^T+b1); C0[t][b][1024:1280] = relu(pre1@W2^T+b2)
  gemm_k<M_RELU><<<dim3(2, 300, 1), 256, 0, stream>>>(frames, pW1b, 576, 576, 256, preb1,
                                                      pre1, 16384, 256, 0, nullptr, nullptr);
  gemm_k<M_RELU><<<dim3(2, 300, 1), 256, 0, stream>>>(pre1, pW2b, 256, 256, 256, preb2,
                                                      C0, 81920, 1280, 1024, nullptr, nullptr);
  // sequential 2-layer LSTM (persistent, 256 blocks x 512 thr, per-wave flags)
  lstm_k<<<dim3(256), 512, 0, stream>>>(C0, H1, W0c, W1c, bih0, bhh0, bih1, bhh1, flags);
  // zero conv pad rows (X bufs were aliased by C0)
  k_zpad<<<gdiv(64 * 4 * 1600), 256, 0, stream>>>(X0, X1, X2);
  // S_pred = h1 @ linW^T + lin_b ; h1[t*64+b] = H1 + 2*64*1024 offset
  gemm_k<M_LINEAR><<<dim3(5, 300, 1), 256, 0, stream>>>(H1 + 131072, linWb, 1024, 1024, 576, linb,
                                                        nullptr, 0, 0, 0, out, X0);
  // postnet
  gemm_k<M_CONVT><<<dim3(4, 5, 64), 256, 0, stream>>>(X0, c1r, 2880, 576, 512, cb1,
                                                      X1, 0, 0, 0, nullptr, nullptr);
  gemm_k<M_CONVT><<<dim3(4, 5, 64), 256, 0, stream>>>(X1, c2r, 2560, 512, 512, cb2,
                                                      X2, 0, 0, 0, nullptr, nullptr);
  gemm_k<M_CONVT><<<dim3(4, 5, 64), 256, 0, stream>>>(X2, c3r, 2560, 512, 512, cb3,
                                                      X1, 0, 0, 0, nullptr, nullptr);
  gemm_k<M_CONVT><<<dim3(4, 5, 64), 256, 0, stream>>>(X1, c4r, 2560, 512, 512, cb4,
                                                      X2, 0, 0, 0, nullptr, nullptr);
  gemm_k<M_CONVF><<<dim3(5, 5, 64), 256, 0, stream>>>(X2, c5r, 2560, 512, 576, cb5,
                                                      nullptr, 0, 0, 0, out, nullptr);
  (void)in_sizes; (void)n_in; (void)out_size; (void)ws_size;
}